// Round 7
// baseline (544.828 us; speedup 1.0000x reference)
//
#include <hip/hip_runtime.h>
#include <hip/hip_bf16.h>

// CktGNN encoder via MFMA. R7: register-resident B matrices.
// Diagnosis R6: latency-bound — every v-step re-streamed ~1 MB of B-frags
// from L2 with ~6 loads in flight (VGPR=64). Fix: B lives in the unified
// VGPR/AGPR file. 16 waves/block; wave w holds j-tile w (and w+16 if w<3):
// 424 regs of B per wave, loaded ONCE in the prologue. Inner loop is pure
// ds_read(A) + MFMA. grid=256, BT=16 n-homogeneous sorted groups (wall time
// is the intrinsic 9-step critical path x now-small step time).
//   GRU ext K=352: [Hin(301) | onehot_t(26) | onehot_p(9) | 1 | pad]
//   gate ext K=320: [H(301) | onehot_p(9) | 1 | pad]

#define HS 301
#define NVT 26
#define MAXPOS 9
#define MAXN 10
#define BSZ 4096
#define VS 310
#define GS 309
#define NZ 56

#define KT1 11          // GRU ext K tiles (K=352)
#define KT2 10          // gate ext K tiles (K=320)
#define NJT 19          // j tiles (ceil(301/16), covers j<304)
#define NB1 (NJT*KT1*3*512)   // f16 count
#define NB2 (NJT*KT2*2*512)   // f16 count

typedef _Float16 f16x8 __attribute__((ext_vector_type(8)));
typedef float f32x4 __attribute__((ext_vector_type(4)));

constexpr int NTH  = 1024;   // 16 waves
constexpr int BT   = 16;
constexpr int NBLK = 256;

__device__ __forceinline__ int fragOff(int g, int k) {
  // byte offset of element (row g, dim k) inside an A-fragment buffer
  return ((k >> 5) << 10) + ((((k & 31) >> 3) << 4) + g) * 16 + ((k & 7) << 1);
}
__device__ __forceinline__ float sigm(float x) { return 1.0f / (1.0f + __expf(-x)); }
__device__ __forceinline__ float tanh_fast(float x) {
  float e = __expf(2.0f * x);
  return 1.0f - 2.0f / (e + 1.0f);
}

// ---------------- sort: counting sort graphs by depth n ----------------
__global__ void ckt_sort(const int* __restrict__ vcount, int* __restrict__ order) {
  __shared__ int cnt[12], off[12];
  int tid = threadIdx.x;
  if (tid < 12) cnt[tid] = 0;
  __syncthreads();
  for (int g = tid; g < BSZ; g += 1024) {
    int n = vcount[g]; n = n < 1 ? 1 : (n > MAXN ? MAXN : n);
    atomicAdd(&cnt[n], 1);
  }
  __syncthreads();
  if (tid == 0) {
    int s = 0;
    for (int i = 1; i <= MAXN; ++i) { off[i] = s; s += cnt[i]; }
  }
  __syncthreads();
  for (int g = tid; g < BSZ; g += 1024) {
    int n = vcount[g]; n = n < 1 ? 1 : (n > MAXN ? MAXN : n);
    int p = atomicAdd(&off[n], 1);
    order[p] = g;
  }
}

// ---------------- prep: pack weights into fragment order ----------------
__global__ void ckt_prep(const float* __restrict__ Wih, const float* __restrict__ Whh,
                         const float* __restrict__ b_ih, const float* __restrict__ b_hh,
                         const float* __restrict__ Wg,  const float* __restrict__ bg,
                         const float* __restrict__ Wm,
                         const float* __restrict__ Wmu, const float* __restrict__ Wlv,
                         unsigned short* __restrict__ B1, unsigned short* __restrict__ B2,
                         float* __restrict__ WnX, float* __restrict__ bn,
                         float* __restrict__ WmuT, float* __restrict__ WlvT)
{
  int i0 = blockIdx.x * blockDim.x + threadIdx.x;
  int str = gridDim.x * blockDim.x;
  // B1: [jt][kt][g3][lane][ii]
  for (int i = i0; i < NB1; i += str) {
    int ii = i & 7, lane = (i >> 3) & 63;
    int r = i >> 9;
    int g3 = r % 3; r /= 3;
    int kt = r % KT1; int jt = r / KT1;
    int j = jt * 16 + (lane & 15);
    int k = kt * 32 + ((lane >> 4) << 3) + ii;
    float val = 0.f;
    if (j < HS) {
      int row = g3 * HS + j;
      if (k < HS) val = Whh[row * HS + k];
      else if (k == 336) val = (g3 < 2) ? (b_ih[row] + b_hh[row]) : b_hh[row];
      else if (g3 < 2) {
        if (k < 327)      val = Wih[row * 35 + (k - 301)];
        else if (k < 336) val = Wih[row * 35 + 26 + (k - 327)];
      }
    }
    B1[i] = __builtin_bit_cast(unsigned short, (_Float16)val);
  }
  // B2: [jt][kt][gm][lane][ii]
  for (int i = i0; i < NB2; i += str) {
    int ii = i & 7, lane = (i >> 3) & 63;
    int r = i >> 9;
    int gm = r % 2; r /= 2;
    int kt = r % KT2; int jt = r / KT2;
    int j = jt * 16 + (lane & 15);
    int k = kt * 32 + ((lane >> 4) << 3) + ii;
    float val = 0.f;
    if (j < HS) {
      const float* W = gm ? Wm : Wg;
      if (k < HS)       val = W[j * VS + k];
      else if (k < 310) val = W[j * VS + HS + (k - 301)];
      else if (k == 310) val = gm ? 0.f : bg[j];
    }
    B2[i] = __builtin_bit_cast(unsigned short, (_Float16)val);
  }
  for (int i = i0; i < 35 * 320; i += str) {
    int x = i / 320, j = i % 320;
    WnX[i] = (j < HS) ? Wih[(2 * HS + j) * 35 + x] : 0.f;
  }
  for (int i = i0; i < 320; i += str) bn[i] = (i < HS) ? b_ih[2 * HS + i] : 0.f;
  for (int i = i0; i < GS * NZ; i += str) {
    int k = i / NZ, o = i % NZ;
    WmuT[i] = Wmu[o * GS + k];
    WlvT[i] = Wlv[o * GS + k];
  }
}

// ---------------- main ----------------
__global__ __launch_bounds__(NTH, 1) void ckt_main(
    const int* __restrict__ node_type, const int* __restrict__ pos,
    const int* __restrict__ adj, const int* __restrict__ vcount,
    const float* __restrict__ rin, const float* __restrict__ cin,
    const float* __restrict__ gmin,
    const float* __restrict__ W1, const float* __restrict__ b1,
    const float* __restrict__ W2, const float* __restrict__ b2,
    const float* __restrict__ bmu, const float* __restrict__ blv,
    const uint4* __restrict__ B1, const uint4* __restrict__ B2,
    const float* __restrict__ WnX, const float* __restrict__ bnG,
    const float* __restrict__ WmuT, const float* __restrict__ WlvT,
    const int* __restrict__ order,
    float* __restrict__ out)
{
  __shared__ __align__(16) _Float16 sGhist[9 * 16 * 304]; // gated history, 87.5 KB
  __shared__ __align__(16) char sAf1[KT1 * 1024];         // GRU A-frags, 11 KB
  __shared__ __align__(16) char sAf2[KT2 * 1024];         // gate A-frags, 10 KB
  __shared__ __align__(16) _Float16 sHg[16 * 304];        // graph state, 9.5 KB
  __shared__ float sBn[320];
  __shared__ int s_gi[16];
  __shared__ int s_t[160], s_p[160], s_n[16];
  __shared__ unsigned s_am[160];
  __shared__ int s_nmax;
  __shared__ float s_df[16][28];
  __shared__ float s_hd[16][16];
  __shared__ float s_hd2[16][8];

  const int tid  = threadIdx.x;
  const int b0   = blockIdx.x * BT;
  const int w    = tid >> 6;          // 0..15
  const int lane = tid & 63;

  if (tid < 16) s_gi[tid] = order[b0 + tid];
  __syncthreads();
  if (tid < 16) {
    int n = vcount[s_gi[tid]];
    s_n[tid] = n < 1 ? 1 : (n > MAXN ? MAXN : n);
    sHg[tid * 304 + 301] = (_Float16)0.f;   // zero f16 pad (heads read f16x8)
    sHg[tid * 304 + 302] = (_Float16)0.f;
    sHg[tid * 304 + 303] = (_Float16)0.f;
  }
  if (tid < 160) {
    int g = tid / 10, vv = tid % 10;
    s_t[tid] = node_type[s_gi[g] * MAXN + vv];
    s_p[tid] = pos[s_gi[g] * MAXN + vv];
  }
  if (tid < 320) sBn[tid] = bnG[tid];
  __syncthreads();
  if (tid < 160) {
    int g = tid / 10, vv = tid % 10;
    unsigned m = 0;
    if (vv < s_n[g]) {
      for (int u = 0; u < vv; ++u)
        if (adj[s_gi[g] * 100 + u * 10 + vv]) m |= (1u << u);
    }
    s_am[tid] = m;
  }
  if (tid == 0) {
    int mx = 1;
    for (int g = 0; g < 16; ++g) mx = max(mx, s_n[g]);
    s_nmax = mx;
  }
  __syncthreads();
  const int nmax = s_nmax;

  const int lq4 = (lane >> 4) << 2;   // base graph row of this lane's D rows
  const int jc  = lane & 15;          // column-within-tile

  // ---------- prologue: load this wave's B slices into registers ----------
  const int  t1   = w;
  const bool has2 = (w < 3);
  const int  t2   = w + 16;
  f16x8 B1a[KT1][3], B1b[KT1][3];
  f16x8 B2a[KT2][2], B2b[KT2][2];
  #pragma unroll
  for (int kt = 0; kt < KT1; ++kt)
    #pragma unroll
    for (int g3 = 0; g3 < 3; ++g3)
      B1a[kt][g3] = __builtin_bit_cast(f16x8, B1[((t1 * KT1 + kt) * 3 + g3) * 64 + lane]);
  #pragma unroll
  for (int kt = 0; kt < KT2; ++kt)
    #pragma unroll
    for (int gm = 0; gm < 2; ++gm)
      B2a[kt][gm] = __builtin_bit_cast(f16x8, B2[((t1 * KT2 + kt) * 2 + gm) * 64 + lane]);
  if (has2) {
    #pragma unroll
    for (int kt = 0; kt < KT1; ++kt)
      #pragma unroll
      for (int g3 = 0; g3 < 3; ++g3)
        B1b[kt][g3] = __builtin_bit_cast(f16x8, B1[((t2 * KT1 + kt) * 3 + g3) * 64 + lane]);
    #pragma unroll
    for (int kt = 0; kt < KT2; ++kt)
      #pragma unroll
      for (int gm = 0; gm < 2; ++gm)
        B2b[kt][gm] = __builtin_bit_cast(f16x8, B2[((t2 * KT2 + kt) * 2 + gm) * 64 + lane]);
  }

  for (int v = 0; v < nmax; ++v) {
    // ---------- phase A: build GRU A-frags + gate one-hot region ----------
    if (tid < KT1 * 64) {              // 704 threads
      int c = tid;
      int kt = c >> 6, ln = c & 63, g = ln & 15;
      int k0 = (kt << 5) + ((ln >> 4) << 3);
      unsigned am = s_am[g * 10 + v];
      f16x8 pk;
      if (k0 + 8 <= HS) {               // pure Hin chunk
        float acc[8];
        #pragma unroll
        for (int e = 0; e < 8; ++e) acc[e] = 0.f;
        for (int u = 0; u < v; ++u) {
          float mf = (float)((am >> u) & 1u);
          f16x8 hh = *(const f16x8*)(sGhist + (u * 16 + g) * 304 + k0);
          #pragma unroll
          for (int e = 0; e < 8; ++e) acc[e] += mf * (float)hh[e];
        }
        #pragma unroll
        for (int e = 0; e < 8; ++e) pk[e] = (_Float16)acc[e];
      } else {                          // boundary / one-hot region
        int t = s_t[g * 10 + v], p = s_p[g * 10 + v];
        #pragma unroll
        for (int e = 0; e < 8; ++e) {
          int k = k0 + e;
          float x = 0.f;
          if (k < HS) {
            for (int u = 0; u < v; ++u) {
              float mf = (float)((am >> u) & 1u);
              x += mf * (float)sGhist[(u * 16 + g) * 304 + k];
            }
          } else if (k < 327) x = (k - 301 == t) ? 1.f : 0.f;
          else if (k < 336)   x = (k - 327 == p) ? 1.f : 0.f;
          else if (k == 336)  x = 1.f;
          pk[e] = (_Float16)x;
        }
      }
      *(f16x8*)(sAf1 + c * 16) = pk;
    } else if (tid - KT1 * 64 < 16 * 19) {  // gate A-frag one-hots k=301..319
      int i = tid - KT1 * 64;
      int g = i / 19, kk = 301 + i % 19;
      float val = (kk < 310) ? ((kk - 301 == s_p[g * 10 + v]) ? 1.f : 0.f)
                             : ((kk == 310) ? 1.f : 0.f);
      *(_Float16*)(sAf2 + fragOff(g, kk)) = (_Float16)val;
    }
    __syncthreads();

    // ---------- GRU GEMM (B from registers) + epilogue ----------
    auto gruTile = [&](const f16x8 (&B)[KT1][3], int jt) {
      f32x4 a0 = {0.f,0.f,0.f,0.f}, a1 = a0, a2 = a0;
      #pragma unroll
      for (int kt = 0; kt < KT1; ++kt) {
        f16x8 av = *(const f16x8*)(sAf1 + kt * 1024 + lane * 16);
        a0 = __builtin_amdgcn_mfma_f32_16x16x32_f16(av, B[kt][0], a0, 0, 0, 0);
        a1 = __builtin_amdgcn_mfma_f32_16x16x32_f16(av, B[kt][1], a1, 0, 0, 0);
        a2 = __builtin_amdgcn_mfma_f32_16x16x32_f16(av, B[kt][2], a2, 0, 0, 0);
      }
      int j = jt * 16 + jc;
      bool jv = j < HS;
      #pragma unroll
      for (int q = 0; q < 4; ++q) {
        int g = lq4 + q;
        float inn = 0.f;
        if (jv) {
          int t = s_t[g * 10 + v], p = s_p[g * 10 + v];
          inn = sBn[j] + WnX[t * 320 + j] + WnX[(26 + p) * 320 + j];
        }
        float rg = sigm(a0[q]);
        float zg = sigm(a1[q]);
        float ng = tanh_fast(inn + rg * a2[q]);
        float hinv = jv ? (float)*(const _Float16*)(sAf1 + fragOff(g, j)) : 0.f;
        float hv = (1.f - zg) * ng + zg * hinv;
        float hval = (v < s_n[g]) ? hv : 0.f;
        if (jv) {
          *(_Float16*)(sAf2 + fragOff(g, j)) = (_Float16)hval;
          if (v == s_n[g] - 1) sHg[g * 304 + j] = (_Float16)hv;
        }
      }
    };
    gruTile(B1a, t1);
    if (has2) gruTile(B1b, t2);
    __syncthreads();

    // ---------- gate/mapper GEMM (B from registers) ----------
    if (v < nmax - 1) {
      auto gateTile = [&](const f16x8 (&B)[KT2][2], int jt) {
        f32x4 c0 = {0.f,0.f,0.f,0.f}, c1 = c0;
        #pragma unroll
        for (int kt = 0; kt < KT2; ++kt) {
          f16x8 av = *(const f16x8*)(sAf2 + kt * 1024 + lane * 16);
          c0 = __builtin_amdgcn_mfma_f32_16x16x32_f16(av, B[kt][0], c0, 0, 0, 0);
          c1 = __builtin_amdgcn_mfma_f32_16x16x32_f16(av, B[kt][1], c1, 0, 0, 0);
        }
        int j = jt * 16 + jc;
        if (j < HS) {
          #pragma unroll
          for (int q = 0; q < 4; ++q) {
            int g = lq4 + q;
            float gg = sigm(c0[q]);
            sGhist[(v * 16 + g) * 304 + j] = (_Float16)(gg * c1[q]);
          }
        }
      };
      gateTile(B2a, t1);
      if (has2) gateTile(B2b, t2);
    }
    __syncthreads();
  }

  // ---------- df feature ----------
  if (tid < 16) {
    int g = tid;
    #pragma unroll
    for (int i2 = 0; i2 < 27; ++i2) s_df[g][i2] = 0.f;
    int n = s_n[g];
    int gi = s_gi[g];
    for (int vv = 0; vv < n; ++vv) {
      int p = s_p[g * 10 + vv];
      int base = gi * MAXN + vv;
      s_df[g][3 * p]     = rin[base];
      s_df[g][3 * p + 1] = cin[base];
      s_df[g][3 * p + 2] = gmin[base];
    }
  }
  __syncthreads();

  // ---------- df_enc ----------
  if (tid < 256) {
    int bb = tid >> 4, o = tid & 15;   // 16x16
    float a = b1[o];
    #pragma unroll
    for (int k = 0; k < 27; ++k) a = fmaf(W1[o * 27 + k], s_df[bb][k], a);
    s_hd[bb][o] = fmaxf(a, 0.f);
  }
  __syncthreads();
  if (tid < 128) {
    int bb = tid >> 3, o = tid & 7;
    float a = b2[o];
    #pragma unroll
    for (int k = 0; k < 16; ++k) a = fmaf(W2[o * 16 + k], s_hd[bb][k], a);
    s_hd2[bb][o] = a;
  }
  __syncthreads();

  // ---------- heads ----------
  if (tid < 2 * NZ) {
    bool ismu = tid < NZ;
    int oo = ismu ? tid : tid - NZ;
    const float* WT = ismu ? WmuT : WlvT;
    float acc[16];
    #pragma unroll
    for (int g = 0; g < 16; ++g) acc[g] = 0.f;
    for (int k0 = 0; k0 < 304; k0 += 8) {
      float wv[8];
      #pragma unroll
      for (int e = 0; e < 8; ++e) {
        int k = k0 + e;
        wv[e] = (k < HS) ? WT[k * NZ + oo] : 0.f;
      }
      #pragma unroll
      for (int g = 0; g < 16; ++g) {
        f16x8 hh = *(const f16x8*)(sHg + g * 304 + k0);
        #pragma unroll
        for (int e = 0; e < 8; ++e) acc[g] += wv[e] * (float)hh[e];
      }
    }
    #pragma unroll
    for (int g = 0; g < 16; ++g) {
      float a = acc[g];
      #pragma unroll
      for (int kk = 0; kk < 8; ++kk) a += WT[(HS + kk) * NZ + oo] * s_hd2[g][kk];
      a += ismu ? bmu[oo] : blv[oo];
      out[(ismu ? 0 : BSZ * NZ) + s_gi[g] * NZ + oo] = a;
    }
  }
}

extern "C" void kernel_launch(void* const* d_in, const int* in_sizes, int n_in,
                              void* d_out, int out_size, void* d_ws, size_t ws_size,
                              hipStream_t stream) {
  const int*   node_type = (const int*)d_in[0];
  const int*   pos       = (const int*)d_in[1];
  const int*   adj       = (const int*)d_in[2];
  const int*   vcount    = (const int*)d_in[3];
  const float* rin       = (const float*)d_in[4];
  const float* cin       = (const float*)d_in[5];
  const float* gmin      = (const float*)d_in[6];
  const float* Wih       = (const float*)d_in[7];
  const float* Whh       = (const float*)d_in[8];
  const float* b_ih      = (const float*)d_in[9];
  const float* b_hh      = (const float*)d_in[10];
  const float* Wg        = (const float*)d_in[11];
  const float* bg        = (const float*)d_in[12];
  const float* Wm        = (const float*)d_in[13];
  const float* W1        = (const float*)d_in[14];
  const float* b1        = (const float*)d_in[15];
  const float* W2        = (const float*)d_in[16];
  const float* b2        = (const float*)d_in[17];
  const float* Wmu       = (const float*)d_in[18];
  const float* bmu       = (const float*)d_in[19];
  const float* Wlv       = (const float*)d_in[20];
  const float* blv       = (const float*)d_in[21];

  // ws layout (bytes, all 16B-aligned)
  char* wsb = (char*)d_ws;
  unsigned short* B1 = (unsigned short*)wsb;              // 642,048 B
  unsigned short* B2 = (unsigned short*)(wsb + 642048);   // 389,120 B
  float* WnX  = (float*)(wsb + 1031168);                  // 44,800 B
  float* bn   = (float*)(wsb + 1075968);                  // 1,280 B
  float* WmuT = (float*)(wsb + 1077248);                  // 69,216 B
  float* WlvT = (float*)(wsb + 1146464);                  // 69,216 B
  int*   order = (int*)(wsb + 1215680);                   // 16,384 B

  ckt_prep<<<512, 256, 0, stream>>>(Wih, Whh, b_ih, b_hh, Wg, bg, Wm, Wmu, Wlv,
                                    B1, B2, WnX, bn, WmuT, WlvT);
  ckt_sort<<<1, 1024, 0, stream>>>(vcount, order);

  ckt_main<<<NBLK, NTH, 0, stream>>>(node_type, pos, adj, vcount, rin, cin, gmin,
      W1, b1, W2, b2, bmu, blv,
      (const uint4*)B1, (const uint4*)B2, WnX, bn, WmuT, WlvT, order, (float*)d_out);
}

// Round 8
// 466.238 us; speedup vs baseline: 1.1686x; 1.1686x over previous
//
#include <hip/hip_runtime.h>
#include <hip/hip_bf16.h>

// CktGNN encoder via MFMA. R8: streaming B with explicit depth-4 register
// pipeline, within the REAL VGPR budget.
// R7 lesson: 1024-thr block = 4 waves/SIMD => hard cap 128 VGPR/wave
// (pool ~512/SIMD). Register-resident B (424 regs) is impossible at this
// occupancy -> compiler scratch-spilled (457MB fetch / 465MB write).
// R8: grid=256, BT=16 sorted groups, 16 waves; wave w streams j-tile w
// (+16+w for w<3) with a depth-4 static-indexed prefetch pipeline
// (12 f16x8 = 48 regs in flight), __launch_bounds__(1024,4).
//   GRU ext K=352: [Hin(301) | onehot_t(26) | onehot_p(9) | 1 | pad]
//   gate ext K=320: [H(301) | onehot_p(9) | 1 | pad]

#define HS 301
#define NVT 26
#define MAXPOS 9
#define MAXN 10
#define BSZ 4096
#define VS 310
#define GS 309
#define NZ 56

#define KT1 11          // GRU ext K tiles (K=352)
#define KT2 10          // gate ext K tiles (K=320)
#define NJT 19          // j tiles (ceil(301/16), covers j<304)
#define NB1 (NJT*KT1*3*512)   // f16 count
#define NB2 (NJT*KT2*2*512)   // f16 count

typedef _Float16 f16x8 __attribute__((ext_vector_type(8)));
typedef float f32x4 __attribute__((ext_vector_type(4)));

constexpr int NTH  = 1024;   // 16 waves
constexpr int BT   = 16;
constexpr int NBLK = 256;

__device__ __forceinline__ int fragOff(int g, int k) {
  // byte offset of element (row g, dim k) inside an A-fragment buffer
  return ((k >> 5) << 10) + ((((k & 31) >> 3) << 4) + g) * 16 + ((k & 7) << 1);
}
__device__ __forceinline__ float sigm(float x) { return 1.0f / (1.0f + __expf(-x)); }
__device__ __forceinline__ float tanh_fast(float x) {
  float e = __expf(2.0f * x);
  return 1.0f - 2.0f / (e + 1.0f);
}

// ---------------- sort: counting sort graphs by depth n ----------------
__global__ void ckt_sort(const int* __restrict__ vcount, int* __restrict__ order) {
  __shared__ int cnt[12], off[12];
  int tid = threadIdx.x;
  if (tid < 12) cnt[tid] = 0;
  __syncthreads();
  for (int g = tid; g < BSZ; g += 1024) {
    int n = vcount[g]; n = n < 1 ? 1 : (n > MAXN ? MAXN : n);
    atomicAdd(&cnt[n], 1);
  }
  __syncthreads();
  if (tid == 0) {
    int s = 0;
    for (int i = 1; i <= MAXN; ++i) { off[i] = s; s += cnt[i]; }
  }
  __syncthreads();
  for (int g = tid; g < BSZ; g += 1024) {
    int n = vcount[g]; n = n < 1 ? 1 : (n > MAXN ? MAXN : n);
    int p = atomicAdd(&off[n], 1);
    order[p] = g;
  }
}

// ---------------- prep: pack weights into fragment order ----------------
__global__ void ckt_prep(const float* __restrict__ Wih, const float* __restrict__ Whh,
                         const float* __restrict__ b_ih, const float* __restrict__ b_hh,
                         const float* __restrict__ Wg,  const float* __restrict__ bg,
                         const float* __restrict__ Wm,
                         const float* __restrict__ Wmu, const float* __restrict__ Wlv,
                         unsigned short* __restrict__ B1, unsigned short* __restrict__ B2,
                         float* __restrict__ WnX, float* __restrict__ bn,
                         float* __restrict__ WmuT, float* __restrict__ WlvT)
{
  int i0 = blockIdx.x * blockDim.x + threadIdx.x;
  int str = gridDim.x * blockDim.x;
  // B1: [jt][kt][g3][lane][ii]
  for (int i = i0; i < NB1; i += str) {
    int ii = i & 7, lane = (i >> 3) & 63;
    int r = i >> 9;
    int g3 = r % 3; r /= 3;
    int kt = r % KT1; int jt = r / KT1;
    int j = jt * 16 + (lane & 15);
    int k = kt * 32 + ((lane >> 4) << 3) + ii;
    float val = 0.f;
    if (j < HS) {
      int row = g3 * HS + j;
      if (k < HS) val = Whh[row * HS + k];
      else if (k == 336) val = (g3 < 2) ? (b_ih[row] + b_hh[row]) : b_hh[row];
      else if (g3 < 2) {
        if (k < 327)      val = Wih[row * 35 + (k - 301)];
        else if (k < 336) val = Wih[row * 35 + 26 + (k - 327)];
      }
    }
    B1[i] = __builtin_bit_cast(unsigned short, (_Float16)val);
  }
  // B2: [jt][kt][gm][lane][ii]
  for (int i = i0; i < NB2; i += str) {
    int ii = i & 7, lane = (i >> 3) & 63;
    int r = i >> 9;
    int gm = r % 2; r /= 2;
    int kt = r % KT2; int jt = r / KT2;
    int j = jt * 16 + (lane & 15);
    int k = kt * 32 + ((lane >> 4) << 3) + ii;
    float val = 0.f;
    if (j < HS) {
      const float* W = gm ? Wm : Wg;
      if (k < HS)       val = W[j * VS + k];
      else if (k < 310) val = W[j * VS + HS + (k - 301)];
      else if (k == 310) val = gm ? 0.f : bg[j];
    }
    B2[i] = __builtin_bit_cast(unsigned short, (_Float16)val);
  }
  for (int i = i0; i < 35 * 320; i += str) {
    int x = i / 320, j = i % 320;
    WnX[i] = (j < HS) ? Wih[(2 * HS + j) * 35 + x] : 0.f;
  }
  for (int i = i0; i < 320; i += str) bn[i] = (i < HS) ? b_ih[2 * HS + i] : 0.f;
  for (int i = i0; i < GS * NZ; i += str) {
    int k = i / NZ, o = i % NZ;
    WmuT[i] = Wmu[o * GS + k];
    WlvT[i] = Wlv[o * GS + k];
  }
}

// ---------------- main ----------------
__global__ __launch_bounds__(NTH, 4) void ckt_main(
    const int* __restrict__ node_type, const int* __restrict__ pos,
    const int* __restrict__ adj, const int* __restrict__ vcount,
    const float* __restrict__ rin, const float* __restrict__ cin,
    const float* __restrict__ gmin,
    const float* __restrict__ W1, const float* __restrict__ b1,
    const float* __restrict__ W2, const float* __restrict__ b2,
    const float* __restrict__ bmu, const float* __restrict__ blv,
    const uint4* __restrict__ B1, const uint4* __restrict__ B2,
    const float* __restrict__ WnX, const float* __restrict__ bnG,
    const float* __restrict__ WmuT, const float* __restrict__ WlvT,
    const int* __restrict__ order,
    float* __restrict__ out)
{
  __shared__ __align__(16) _Float16 sGhist[9 * 16 * 304]; // gated history, 87.5 KB
  __shared__ __align__(16) char sAf1[KT1 * 1024];         // GRU A-frags, 11 KB
  __shared__ __align__(16) char sAf2[KT2 * 1024];         // gate A-frags, 10 KB
  __shared__ __align__(16) _Float16 sHg[16 * 304];        // graph state, 9.5 KB
  __shared__ float sBn[320];
  __shared__ int s_gi[16];
  __shared__ int s_t[160], s_p[160], s_n[16];
  __shared__ unsigned s_am[160];
  __shared__ int s_nmax;
  __shared__ float s_df[16][28];
  __shared__ float s_hd[16][16];
  __shared__ float s_hd2[16][8];

  const int tid  = threadIdx.x;
  const int b0   = blockIdx.x * BT;
  const int w    = tid >> 6;          // 0..15
  const int lane = tid & 63;

  if (tid < 16) s_gi[tid] = order[b0 + tid];
  __syncthreads();
  if (tid < 16) {
    int n = vcount[s_gi[tid]];
    s_n[tid] = n < 1 ? 1 : (n > MAXN ? MAXN : n);
    sHg[tid * 304 + 301] = (_Float16)0.f;   // zero f16 pad (heads read f16x8)
    sHg[tid * 304 + 302] = (_Float16)0.f;
    sHg[tid * 304 + 303] = (_Float16)0.f;
  }
  if (tid < 160) {
    int g = tid / 10, vv = tid % 10;
    s_t[tid] = node_type[s_gi[g] * MAXN + vv];
    s_p[tid] = pos[s_gi[g] * MAXN + vv];
  }
  if (tid < 320) sBn[tid] = bnG[tid];
  __syncthreads();
  if (tid < 160) {
    int g = tid / 10, vv = tid % 10;
    unsigned m = 0;
    if (vv < s_n[g]) {
      for (int u = 0; u < vv; ++u)
        if (adj[s_gi[g] * 100 + u * 10 + vv]) m |= (1u << u);
    }
    s_am[tid] = m;
  }
  if (tid == 0) {
    int mx = 1;
    for (int g = 0; g < 16; ++g) mx = max(mx, s_n[g]);
    s_nmax = mx;
  }
  __syncthreads();
  const int nmax = s_nmax;

  const int lq4 = (lane >> 4) << 2;   // base graph row of this lane's D rows
  const int jc  = lane & 15;          // column-within-tile
  const bool has2 = (w < 3);
  const int  t2   = w + 16;

  for (int v = 0; v < nmax; ++v) {
    // ---------- phase A: build GRU A-frags + gate one-hot region ----------
    if (tid < KT1 * 64) {              // 704 threads
      int c = tid;
      int kt = c >> 6, ln = c & 63, g = ln & 15;
      int k0 = (kt << 5) + ((ln >> 4) << 3);
      unsigned am = s_am[g * 10 + v];
      f16x8 pk;
      if (k0 + 8 <= HS) {               // pure Hin chunk
        float acc[8];
        #pragma unroll
        for (int e = 0; e < 8; ++e) acc[e] = 0.f;
        for (int u = 0; u < v; ++u) {
          float mf = (float)((am >> u) & 1u);
          f16x8 hh = *(const f16x8*)(sGhist + (u * 16 + g) * 304 + k0);
          #pragma unroll
          for (int e = 0; e < 8; ++e) acc[e] += mf * (float)hh[e];
        }
        #pragma unroll
        for (int e = 0; e < 8; ++e) pk[e] = (_Float16)acc[e];
      } else {                          // boundary / one-hot region
        int t = s_t[g * 10 + v], p = s_p[g * 10 + v];
        #pragma unroll
        for (int e = 0; e < 8; ++e) {
          int k = k0 + e;
          float x = 0.f;
          if (k < HS) {
            for (int u = 0; u < v; ++u) {
              float mf = (float)((am >> u) & 1u);
              x += mf * (float)sGhist[(u * 16 + g) * 304 + k];
            }
          } else if (k < 327) x = (k - 301 == t) ? 1.f : 0.f;
          else if (k < 336)   x = (k - 327 == p) ? 1.f : 0.f;
          else if (k == 336)  x = 1.f;
          pk[e] = (_Float16)x;
        }
      }
      *(f16x8*)(sAf1 + c * 16) = pk;
    } else if (tid - KT1 * 64 < 16 * 19) {  // gate A-frag one-hots k=301..319
      int i = tid - KT1 * 64;
      int g = i / 19, kk = 301 + i % 19;
      float val = (kk < 310) ? ((kk - 301 == s_p[g * 10 + v]) ? 1.f : 0.f)
                             : ((kk == 310) ? 1.f : 0.f);
      *(_Float16*)(sAf2 + fragOff(g, kk)) = (_Float16)val;
    }
    __syncthreads();

    // ---------- GRU GEMM: depth-4 pipelined B stream ----------
    auto gruTile = [&](int jt) {
      const uint4* Bp = B1 + (size_t)jt * (KT1 * 3 * 64) + lane;
      f16x8 pb[4][3];                    // 48 regs, statically indexed
      #pragma unroll
      for (int s = 0; s < 4; ++s)
        #pragma unroll
        for (int g3 = 0; g3 < 3; ++g3)
          pb[s][g3] = __builtin_bit_cast(f16x8, Bp[(s * 3 + g3) * 64]);
      f32x4 a0 = {0.f,0.f,0.f,0.f}, a1 = a0, a2 = a0;
      #pragma unroll
      for (int kt = 0; kt < KT1; ++kt) {
        f16x8 av = *(const f16x8*)(sAf1 + kt * 1024 + lane * 16);
        f16x8 c0 = pb[kt & 3][0], c1 = pb[kt & 3][1], c2 = pb[kt & 3][2];
        if (kt + 4 < KT1) {
          #pragma unroll
          for (int g3 = 0; g3 < 3; ++g3)
            pb[kt & 3][g3] = __builtin_bit_cast(f16x8, Bp[((kt + 4) * 3 + g3) * 64]);
        }
        a0 = __builtin_amdgcn_mfma_f32_16x16x32_f16(av, c0, a0, 0, 0, 0);
        a1 = __builtin_amdgcn_mfma_f32_16x16x32_f16(av, c1, a1, 0, 0, 0);
        a2 = __builtin_amdgcn_mfma_f32_16x16x32_f16(av, c2, a2, 0, 0, 0);
      }
      int j = jt * 16 + jc;
      bool jv = j < HS;
      #pragma unroll
      for (int q = 0; q < 4; ++q) {
        int g = lq4 + q;
        float inn = 0.f;
        if (jv) {
          int t = s_t[g * 10 + v], p = s_p[g * 10 + v];
          inn = sBn[j] + WnX[t * 320 + j] + WnX[(26 + p) * 320 + j];
        }
        float rg = sigm(a0[q]);
        float zg = sigm(a1[q]);
        float ng = tanh_fast(inn + rg * a2[q]);
        float hinv = jv ? (float)*(const _Float16*)(sAf1 + fragOff(g, j)) : 0.f;
        float hv = (1.f - zg) * ng + zg * hinv;
        float hval = (v < s_n[g]) ? hv : 0.f;
        if (jv) {
          *(_Float16*)(sAf2 + fragOff(g, j)) = (_Float16)hval;
          if (v == s_n[g] - 1) sHg[g * 304 + j] = (_Float16)hv;
        }
      }
    };
    gruTile(w);
    if (has2) gruTile(t2);
    __syncthreads();

    // ---------- gate/mapper GEMM: depth-4 pipelined B stream ----------
    if (v < nmax - 1) {
      auto gateTile = [&](int jt) {
        const uint4* Bp = B2 + (size_t)jt * (KT2 * 2 * 64) + lane;
        f16x8 pb[4][2];                  // 32 regs
        #pragma unroll
        for (int s = 0; s < 4; ++s)
          #pragma unroll
          for (int gm = 0; gm < 2; ++gm)
            pb[s][gm] = __builtin_bit_cast(f16x8, Bp[(s * 2 + gm) * 64]);
        f32x4 c0 = {0.f,0.f,0.f,0.f}, c1 = c0;
        #pragma unroll
        for (int kt = 0; kt < KT2; ++kt) {
          f16x8 av = *(const f16x8*)(sAf2 + kt * 1024 + lane * 16);
          f16x8 d0 = pb[kt & 3][0], d1 = pb[kt & 3][1];
          if (kt + 4 < KT2) {
            #pragma unroll
            for (int gm = 0; gm < 2; ++gm)
              pb[kt & 3][gm] = __builtin_bit_cast(f16x8, Bp[((kt + 4) * 2 + gm) * 64]);
          }
          c0 = __builtin_amdgcn_mfma_f32_16x16x32_f16(av, d0, c0, 0, 0, 0);
          c1 = __builtin_amdgcn_mfma_f32_16x16x32_f16(av, d1, c1, 0, 0, 0);
        }
        int j = jt * 16 + jc;
        if (j < HS) {
          #pragma unroll
          for (int q = 0; q < 4; ++q) {
            int g = lq4 + q;
            float gg = sigm(c0[q]);
            sGhist[(v * 16 + g) * 304 + j] = (_Float16)(gg * c1[q]);
          }
        }
      };
      gateTile(w);
      if (has2) gateTile(t2);
    }
    __syncthreads();
  }

  // ---------- df feature ----------
  if (tid < 16) {
    int g = tid;
    #pragma unroll
    for (int i2 = 0; i2 < 27; ++i2) s_df[g][i2] = 0.f;
    int n = s_n[g];
    int gi = s_gi[g];
    for (int vv = 0; vv < n; ++vv) {
      int p = s_p[g * 10 + vv];
      int base = gi * MAXN + vv;
      s_df[g][3 * p]     = rin[base];
      s_df[g][3 * p + 1] = cin[base];
      s_df[g][3 * p + 2] = gmin[base];
    }
  }
  __syncthreads();

  // ---------- df_enc ----------
  if (tid < 256) {
    int bb = tid >> 4, o = tid & 15;   // 16x16
    float a = b1[o];
    #pragma unroll
    for (int k = 0; k < 27; ++k) a = fmaf(W1[o * 27 + k], s_df[bb][k], a);
    s_hd[bb][o] = fmaxf(a, 0.f);
  }
  __syncthreads();
  if (tid < 128) {
    int bb = tid >> 3, o = tid & 7;
    float a = b2[o];
    #pragma unroll
    for (int k = 0; k < 16; ++k) a = fmaf(W2[o * 16 + k], s_hd[bb][k], a);
    s_hd2[bb][o] = a;
  }
  __syncthreads();

  // ---------- heads ----------
  if (tid < 2 * NZ) {
    bool ismu = tid < NZ;
    int oo = ismu ? tid : tid - NZ;
    const float* WT = ismu ? WmuT : WlvT;
    float acc[16];
    #pragma unroll
    for (int g = 0; g < 16; ++g) acc[g] = 0.f;
    for (int k0 = 0; k0 < 304; k0 += 8) {
      float wv[8];
      #pragma unroll
      for (int e = 0; e < 8; ++e) {
        int k = k0 + e;
        wv[e] = (k < HS) ? WT[k * NZ + oo] : 0.f;
      }
      #pragma unroll
      for (int g = 0; g < 16; ++g) {
        f16x8 hh = *(const f16x8*)(sHg + g * 304 + k0);
        #pragma unroll
        for (int e = 0; e < 8; ++e) acc[g] += wv[e] * (float)hh[e];
      }
    }
    #pragma unroll
    for (int g = 0; g < 16; ++g) {
      float a = acc[g];
      #pragma unroll
      for (int kk = 0; kk < 8; ++kk) a += WT[(HS + kk) * NZ + oo] * s_hd2[g][kk];
      a += ismu ? bmu[oo] : blv[oo];
      out[(ismu ? 0 : BSZ * NZ) + s_gi[g] * NZ + oo] = a;
    }
  }
}

extern "C" void kernel_launch(void* const* d_in, const int* in_sizes, int n_in,
                              void* d_out, int out_size, void* d_ws, size_t ws_size,
                              hipStream_t stream) {
  const int*   node_type = (const int*)d_in[0];
  const int*   pos       = (const int*)d_in[1];
  const int*   adj       = (const int*)d_in[2];
  const int*   vcount    = (const int*)d_in[3];
  const float* rin       = (const float*)d_in[4];
  const float* cin       = (const float*)d_in[5];
  const float* gmin      = (const float*)d_in[6];
  const float* Wih       = (const float*)d_in[7];
  const float* Whh       = (const float*)d_in[8];
  const float* b_ih      = (const float*)d_in[9];
  const float* b_hh      = (const float*)d_in[10];
  const float* Wg        = (const float*)d_in[11];
  const float* bg        = (const float*)d_in[12];
  const float* Wm        = (const float*)d_in[13];
  const float* W1        = (const float*)d_in[14];
  const float* b1        = (const float*)d_in[15];
  const float* W2        = (const float*)d_in[16];
  const float* b2        = (const float*)d_in[17];
  const float* Wmu       = (const float*)d_in[18];
  const float* bmu       = (const float*)d_in[19];
  const float* Wlv       = (const float*)d_in[20];
  const float* blv       = (const float*)d_in[21];

  // ws layout (bytes, all 16B-aligned)
  char* wsb = (char*)d_ws;
  unsigned short* B1 = (unsigned short*)wsb;              // 642,048 B
  unsigned short* B2 = (unsigned short*)(wsb + 642048);   // 389,120 B
  float* WnX  = (float*)(wsb + 1031168);                  // 44,800 B
  float* bn   = (float*)(wsb + 1075968);                  // 1,280 B
  float* WmuT = (float*)(wsb + 1077248);                  // 69,216 B
  float* WlvT = (float*)(wsb + 1146464);                  // 69,216 B
  int*   order = (int*)(wsb + 1215680);                   // 16,384 B

  ckt_prep<<<512, 256, 0, stream>>>(Wih, Whh, b_ih, b_hh, Wg, bg, Wm, Wmu, Wlv,
                                    B1, B2, WnX, bn, WmuT, WlvT);
  ckt_sort<<<1, 1024, 0, stream>>>(vcount, order);

  ckt_main<<<NBLK, NTH, 0, stream>>>(node_type, pos, adj, vcount, rin, cin, gmin,
      W1, b1, W2, b2, bmu, blv,
      (const uint4*)B1, (const uint4*)B2, WnX, bn, WmuT, WlvT, order, (float*)d_out);
}

// Round 9
// 460.464 us; speedup vs baseline: 1.1832x; 1.0125x over previous
//
#include <hip/hip_runtime.h>
#include <hip/hip_bf16.h>

// CktGNN encoder via MFMA. R9: depth-4 B prefetch with NAMED registers.
// R8 lesson (rule #20): f16x8 pb[4][3] arrays got demoted to scratch
// (VGPR=64, 255MB scratch writes) even with static indices after unroll.
// R9: macro-expanded straight-line pipeline, individually named f16x8 slots
// -> no arrays -> no demotion. grid=256, BT=16 sorted groups, 16 waves,
// __launch_bounds__(1024,4) => 128 VGPR cap; expect ~96-128 used.
//   GRU ext K=352: [Hin(301) | onehot_t(26) | onehot_p(9) | 1 | pad]
//   gate ext K=320: [H(301) | onehot_p(9) | 1 | pad]

#define HS 301
#define NVT 26
#define MAXPOS 9
#define MAXN 10
#define BSZ 4096
#define VS 310
#define GS 309
#define NZ 56

#define KT1 11          // GRU ext K tiles (K=352)
#define KT2 10          // gate ext K tiles (K=320)
#define NJT 19          // j tiles (ceil(301/16), covers j<304)
#define NB1 (NJT*KT1*3*512)   // f16 count
#define NB2 (NJT*KT2*2*512)   // f16 count

typedef _Float16 f16x8 __attribute__((ext_vector_type(8)));
typedef float f32x4 __attribute__((ext_vector_type(4)));

constexpr int NTH  = 1024;   // 16 waves
constexpr int BT   = 16;
constexpr int NBLK = 256;

__device__ __forceinline__ int fragOff(int g, int k) {
  // byte offset of element (row g, dim k) inside an A-fragment buffer
  return ((k >> 5) << 10) + ((((k & 31) >> 3) << 4) + g) * 16 + ((k & 7) << 1);
}
__device__ __forceinline__ float sigm(float x) { return 1.0f / (1.0f + __expf(-x)); }
__device__ __forceinline__ float tanh_fast(float x) {
  float e = __expf(2.0f * x);
  return 1.0f - 2.0f / (e + 1.0f);
}
#define BC(x) __builtin_bit_cast(f16x8, (x))

// ---------------- sort: counting sort graphs by depth n ----------------
__global__ void ckt_sort(const int* __restrict__ vcount, int* __restrict__ order) {
  __shared__ int cnt[12], off[12];
  int tid = threadIdx.x;
  if (tid < 12) cnt[tid] = 0;
  __syncthreads();
  for (int g = tid; g < BSZ; g += 1024) {
    int n = vcount[g]; n = n < 1 ? 1 : (n > MAXN ? MAXN : n);
    atomicAdd(&cnt[n], 1);
  }
  __syncthreads();
  if (tid == 0) {
    int s = 0;
    for (int i = 1; i <= MAXN; ++i) { off[i] = s; s += cnt[i]; }
  }
  __syncthreads();
  for (int g = tid; g < BSZ; g += 1024) {
    int n = vcount[g]; n = n < 1 ? 1 : (n > MAXN ? MAXN : n);
    int p = atomicAdd(&off[n], 1);
    order[p] = g;
  }
}

// ---------------- prep: pack weights into fragment order ----------------
__global__ void ckt_prep(const float* __restrict__ Wih, const float* __restrict__ Whh,
                         const float* __restrict__ b_ih, const float* __restrict__ b_hh,
                         const float* __restrict__ Wg,  const float* __restrict__ bg,
                         const float* __restrict__ Wm,
                         const float* __restrict__ Wmu, const float* __restrict__ Wlv,
                         unsigned short* __restrict__ B1, unsigned short* __restrict__ B2,
                         float* __restrict__ WnX, float* __restrict__ bn,
                         float* __restrict__ WmuT, float* __restrict__ WlvT)
{
  int i0 = blockIdx.x * blockDim.x + threadIdx.x;
  int str = gridDim.x * blockDim.x;
  // B1: [jt][kt][g3][lane][ii]
  for (int i = i0; i < NB1; i += str) {
    int ii = i & 7, lane = (i >> 3) & 63;
    int r = i >> 9;
    int g3 = r % 3; r /= 3;
    int kt = r % KT1; int jt = r / KT1;
    int j = jt * 16 + (lane & 15);
    int k = kt * 32 + ((lane >> 4) << 3) + ii;
    float val = 0.f;
    if (j < HS) {
      int row = g3 * HS + j;
      if (k < HS) val = Whh[row * HS + k];
      else if (k == 336) val = (g3 < 2) ? (b_ih[row] + b_hh[row]) : b_hh[row];
      else if (g3 < 2) {
        if (k < 327)      val = Wih[row * 35 + (k - 301)];
        else if (k < 336) val = Wih[row * 35 + 26 + (k - 327)];
      }
    }
    B1[i] = __builtin_bit_cast(unsigned short, (_Float16)val);
  }
  // B2: [jt][kt][gm][lane][ii]
  for (int i = i0; i < NB2; i += str) {
    int ii = i & 7, lane = (i >> 3) & 63;
    int r = i >> 9;
    int gm = r % 2; r /= 2;
    int kt = r % KT2; int jt = r / KT2;
    int j = jt * 16 + (lane & 15);
    int k = kt * 32 + ((lane >> 4) << 3) + ii;
    float val = 0.f;
    if (j < HS) {
      const float* W = gm ? Wm : Wg;
      if (k < HS)       val = W[j * VS + k];
      else if (k < 310) val = W[j * VS + HS + (k - 301)];
      else if (k == 310) val = gm ? 0.f : bg[j];
    }
    B2[i] = __builtin_bit_cast(unsigned short, (_Float16)val);
  }
  for (int i = i0; i < 35 * 320; i += str) {
    int x = i / 320, j = i % 320;
    WnX[i] = (j < HS) ? Wih[(2 * HS + j) * 35 + x] : 0.f;
  }
  for (int i = i0; i < 320; i += str) bn[i] = (i < HS) ? b_ih[2 * HS + i] : 0.f;
  for (int i = i0; i < GS * NZ; i += str) {
    int k = i / NZ, o = i % NZ;
    WmuT[i] = Wmu[o * GS + k];
    WlvT[i] = Wlv[o * GS + k];
  }
}

// ---------------- main ----------------
__global__ __launch_bounds__(NTH, 4) void ckt_main(
    const int* __restrict__ node_type, const int* __restrict__ pos,
    const int* __restrict__ adj, const int* __restrict__ vcount,
    const float* __restrict__ rin, const float* __restrict__ cin,
    const float* __restrict__ gmin,
    const float* __restrict__ W1, const float* __restrict__ b1,
    const float* __restrict__ W2, const float* __restrict__ b2,
    const float* __restrict__ bmu, const float* __restrict__ blv,
    const uint4* __restrict__ B1, const uint4* __restrict__ B2,
    const float* __restrict__ WnX, const float* __restrict__ bnG,
    const float* __restrict__ WmuT, const float* __restrict__ WlvT,
    const int* __restrict__ order,
    float* __restrict__ out)
{
  __shared__ __align__(16) _Float16 sGhist[9 * 16 * 304]; // gated history, 87.5 KB
  __shared__ __align__(16) char sAf1[KT1 * 1024];         // GRU A-frags, 11 KB
  __shared__ __align__(16) char sAf2[KT2 * 1024];         // gate A-frags, 10 KB
  __shared__ __align__(16) _Float16 sHg[16 * 304];        // graph state, 9.5 KB
  __shared__ float sBn[320];
  __shared__ int s_gi[16];
  __shared__ int s_t[160], s_p[160], s_n[16];
  __shared__ unsigned s_am[160];
  __shared__ int s_nmax;
  __shared__ float s_df[16][28];
  __shared__ float s_hd[16][16];
  __shared__ float s_hd2[16][8];

  const int tid  = threadIdx.x;
  const int b0   = blockIdx.x * BT;
  const int w    = tid >> 6;          // 0..15
  const int lane = tid & 63;

  if (tid < 16) s_gi[tid] = order[b0 + tid];
  __syncthreads();
  if (tid < 16) {
    int n = vcount[s_gi[tid]];
    s_n[tid] = n < 1 ? 1 : (n > MAXN ? MAXN : n);
    sHg[tid * 304 + 301] = (_Float16)0.f;   // zero f16 pad (heads read f16x8)
    sHg[tid * 304 + 302] = (_Float16)0.f;
    sHg[tid * 304 + 303] = (_Float16)0.f;
  }
  if (tid < 160) {
    int g = tid / 10, vv = tid % 10;
    s_t[tid] = node_type[s_gi[g] * MAXN + vv];
    s_p[tid] = pos[s_gi[g] * MAXN + vv];
  }
  if (tid < 320) sBn[tid] = bnG[tid];
  __syncthreads();
  if (tid < 160) {
    int g = tid / 10, vv = tid % 10;
    unsigned m = 0;
    if (vv < s_n[g]) {
      for (int u = 0; u < vv; ++u)
        if (adj[s_gi[g] * 100 + u * 10 + vv]) m |= (1u << u);
    }
    s_am[tid] = m;
  }
  if (tid == 0) {
    int mx = 1;
    for (int g = 0; g < 16; ++g) mx = max(mx, s_n[g]);
    s_nmax = mx;
  }
  __syncthreads();
  const int nmax = s_nmax;

  const int lq4 = (lane >> 4) << 2;   // base graph row of this lane's D rows
  const int jc  = lane & 15;          // column-within-tile
  const bool has2 = (w < 3);
  const int  t2   = w + 16;

  for (int v = 0; v < nmax; ++v) {
    // ---------- phase A: build GRU A-frags + gate one-hot region ----------
    if (tid < KT1 * 64) {              // 704 threads
      int c = tid;
      int kt = c >> 6, ln = c & 63, g = ln & 15;
      int k0 = (kt << 5) + ((ln >> 4) << 3);
      unsigned am = s_am[g * 10 + v];
      f16x8 pk;
      if (k0 + 8 <= HS) {               // pure Hin chunk
        float acc0 = 0.f, acc1 = 0.f, acc2 = 0.f, acc3 = 0.f;
        float acc4 = 0.f, acc5 = 0.f, acc6 = 0.f, acc7 = 0.f;
        for (int u = 0; u < v; ++u) {
          float mf = (float)((am >> u) & 1u);
          f16x8 hh = *(const f16x8*)(sGhist + (u * 16 + g) * 304 + k0);
          acc0 += mf * (float)hh[0]; acc1 += mf * (float)hh[1];
          acc2 += mf * (float)hh[2]; acc3 += mf * (float)hh[3];
          acc4 += mf * (float)hh[4]; acc5 += mf * (float)hh[5];
          acc6 += mf * (float)hh[6]; acc7 += mf * (float)hh[7];
        }
        pk[0] = (_Float16)acc0; pk[1] = (_Float16)acc1;
        pk[2] = (_Float16)acc2; pk[3] = (_Float16)acc3;
        pk[4] = (_Float16)acc4; pk[5] = (_Float16)acc5;
        pk[6] = (_Float16)acc6; pk[7] = (_Float16)acc7;
      } else {                          // boundary / one-hot region
        int t = s_t[g * 10 + v], p = s_p[g * 10 + v];
        #pragma unroll
        for (int e = 0; e < 8; ++e) {
          int k = k0 + e;
          float x = 0.f;
          if (k < HS) {
            for (int u = 0; u < v; ++u) {
              float mf = (float)((am >> u) & 1u);
              x += mf * (float)sGhist[(u * 16 + g) * 304 + k];
            }
          } else if (k < 327) x = (k - 301 == t) ? 1.f : 0.f;
          else if (k < 336)   x = (k - 327 == p) ? 1.f : 0.f;
          else if (k == 336)  x = 1.f;
          pk[e] = (_Float16)x;
        }
      }
      *(f16x8*)(sAf1 + c * 16) = pk;
    } else if (tid - KT1 * 64 < 16 * 19) {  // gate A-frag one-hots k=301..319
      int i = tid - KT1 * 64;
      int g = i / 19, kk = 301 + i % 19;
      float val = (kk < 310) ? ((kk - 301 == s_p[g * 10 + v]) ? 1.f : 0.f)
                             : ((kk == 310) ? 1.f : 0.f);
      *(_Float16*)(sAf2 + fragOff(g, kk)) = (_Float16)val;
    }
    __syncthreads();

    // ---------- GRU GEMM: depth-4 pipeline, NAMED slots ----------
    auto gruTile = [&](int jt) {
      const uint4* Bp = B1 + (size_t)jt * (KT1 * 3 * 64) + lane;
      f16x8 p00, p01, p02, p10, p11, p12, p20, p21, p22, p30, p31, p32;
#define LB1(P0, P1, P2, KT) \
      P0 = BC(Bp[((KT) * 3 + 0) * 64]); \
      P1 = BC(Bp[((KT) * 3 + 1) * 64]); \
      P2 = BC(Bp[((KT) * 3 + 2) * 64]);
      LB1(p00, p01, p02, 0) LB1(p10, p11, p12, 1)
      LB1(p20, p21, p22, 2) LB1(p30, p31, p32, 3)
      f32x4 a0 = {0.f, 0.f, 0.f, 0.f}, a1 = a0, a2 = a0;
#define ST1(P0, P1, P2, KT, KTN) { \
      f16x8 av = *(const f16x8*)(sAf1 + (KT) * 1024 + lane * 16); \
      f16x8 c0 = P0, c1 = P1, c2 = P2; \
      LB1(P0, P1, P2, KTN) \
      a0 = __builtin_amdgcn_mfma_f32_16x16x32_f16(av, c0, a0, 0, 0, 0); \
      a1 = __builtin_amdgcn_mfma_f32_16x16x32_f16(av, c1, a1, 0, 0, 0); \
      a2 = __builtin_amdgcn_mfma_f32_16x16x32_f16(av, c2, a2, 0, 0, 0); }
#define ST1E(P0, P1, P2, KT) { \
      f16x8 av = *(const f16x8*)(sAf1 + (KT) * 1024 + lane * 16); \
      a0 = __builtin_amdgcn_mfma_f32_16x16x32_f16(av, P0, a0, 0, 0, 0); \
      a1 = __builtin_amdgcn_mfma_f32_16x16x32_f16(av, P1, a1, 0, 0, 0); \
      a2 = __builtin_amdgcn_mfma_f32_16x16x32_f16(av, P2, a2, 0, 0, 0); }
      ST1(p00, p01, p02, 0, 4) ST1(p10, p11, p12, 1, 5)
      ST1(p20, p21, p22, 2, 6) ST1(p30, p31, p32, 3, 7)
      ST1(p00, p01, p02, 4, 8) ST1(p10, p11, p12, 5, 9)
      ST1(p20, p21, p22, 6, 10)
      ST1E(p30, p31, p32, 7) ST1E(p00, p01, p02, 8)
      ST1E(p10, p11, p12, 9) ST1E(p20, p21, p22, 10)
#undef ST1
#undef ST1E
#undef LB1
      int j = jt * 16 + jc;
      bool jv = j < HS;
      #pragma unroll
      for (int q = 0; q < 4; ++q) {
        int g = lq4 + q;
        float inn = 0.f;
        if (jv) {
          int t = s_t[g * 10 + v], p = s_p[g * 10 + v];
          inn = sBn[j] + WnX[t * 320 + j] + WnX[(26 + p) * 320 + j];
        }
        float rg = sigm(a0[q]);
        float zg = sigm(a1[q]);
        float ng = tanh_fast(inn + rg * a2[q]);
        float hinv = jv ? (float)*(const _Float16*)(sAf1 + fragOff(g, j)) : 0.f;
        float hv = (1.f - zg) * ng + zg * hinv;
        float hval = (v < s_n[g]) ? hv : 0.f;
        if (jv) {
          *(_Float16*)(sAf2 + fragOff(g, j)) = (_Float16)hval;
          if (v == s_n[g] - 1) sHg[g * 304 + j] = (_Float16)hv;
        }
      }
    };
    gruTile(w);
    if (has2) gruTile(t2);
    __syncthreads();

    // ---------- gate/mapper GEMM: depth-4 pipeline, NAMED slots ----------
    if (v < nmax - 1) {
      auto gateTile = [&](int jt) {
        const uint4* Bp = B2 + (size_t)jt * (KT2 * 2 * 64) + lane;
        f16x8 q00, q01, q10, q11, q20, q21, q30, q31;
#define LB2(P0, P1, KT) \
        P0 = BC(Bp[((KT) * 2 + 0) * 64]); \
        P1 = BC(Bp[((KT) * 2 + 1) * 64]);
        LB2(q00, q01, 0) LB2(q10, q11, 1) LB2(q20, q21, 2) LB2(q30, q31, 3)
        f32x4 c0 = {0.f, 0.f, 0.f, 0.f}, c1 = c0;
#define ST2(P0, P1, KT, KTN) { \
        f16x8 av = *(const f16x8*)(sAf2 + (KT) * 1024 + lane * 16); \
        f16x8 d0 = P0, d1 = P1; \
        LB2(P0, P1, KTN) \
        c0 = __builtin_amdgcn_mfma_f32_16x16x32_f16(av, d0, c0, 0, 0, 0); \
        c1 = __builtin_amdgcn_mfma_f32_16x16x32_f16(av, d1, c1, 0, 0, 0); }
#define ST2E(P0, P1, KT) { \
        f16x8 av = *(const f16x8*)(sAf2 + (KT) * 1024 + lane * 16); \
        c0 = __builtin_amdgcn_mfma_f32_16x16x32_f16(av, P0, c0, 0, 0, 0); \
        c1 = __builtin_amdgcn_mfma_f32_16x16x32_f16(av, P1, c1, 0, 0, 0); }
        ST2(q00, q01, 0, 4) ST2(q10, q11, 1, 5) ST2(q20, q21, 2, 6)
        ST2(q30, q31, 3, 7) ST2(q00, q01, 4, 8) ST2(q10, q11, 5, 9)
        ST2E(q20, q21, 6) ST2E(q30, q31, 7) ST2E(q00, q01, 8) ST2E(q10, q11, 9)
#undef ST2
#undef ST2E
#undef LB2
        int j = jt * 16 + jc;
        if (j < HS) {
          #pragma unroll
          for (int q = 0; q < 4; ++q) {
            int g = lq4 + q;
            float gg = sigm(c0[q]);
            sGhist[(v * 16 + g) * 304 + j] = (_Float16)(gg * c1[q]);
          }
        }
      };
      gateTile(w);
      if (has2) gateTile(t2);
    }
    __syncthreads();
  }

  // ---------- df feature ----------
  if (tid < 16) {
    int g = tid;
    #pragma unroll
    for (int i2 = 0; i2 < 27; ++i2) s_df[g][i2] = 0.f;
    int n = s_n[g];
    int gi = s_gi[g];
    for (int vv = 0; vv < n; ++vv) {
      int p = s_p[g * 10 + vv];
      int base = gi * MAXN + vv;
      s_df[g][3 * p]     = rin[base];
      s_df[g][3 * p + 1] = cin[base];
      s_df[g][3 * p + 2] = gmin[base];
    }
  }
  __syncthreads();

  // ---------- df_enc ----------
  if (tid < 256) {
    int bb = tid >> 4, o = tid & 15;   // 16x16
    float a = b1[o];
    #pragma unroll
    for (int k = 0; k < 27; ++k) a = fmaf(W1[o * 27 + k], s_df[bb][k], a);
    s_hd[bb][o] = fmaxf(a, 0.f);
  }
  __syncthreads();
  if (tid < 128) {
    int bb = tid >> 3, o = tid & 7;
    float a = b2[o];
    #pragma unroll
    for (int k = 0; k < 16; ++k) a = fmaf(W2[o * 16 + k], s_hd[bb][k], a);
    s_hd2[bb][o] = a;
  }
  __syncthreads();

  // ---------- heads ----------
  if (tid < 2 * NZ) {
    bool ismu = tid < NZ;
    int oo = ismu ? tid : tid - NZ;
    const float* WT = ismu ? WmuT : WlvT;
    float acc[16];
    #pragma unroll
    for (int g = 0; g < 16; ++g) acc[g] = 0.f;
    for (int k0 = 0; k0 < 304; k0 += 8) {
      float wv[8];
      #pragma unroll
      for (int e = 0; e < 8; ++e) {
        int k = k0 + e;
        wv[e] = (k < HS) ? WT[k * NZ + oo] : 0.f;
      }
      #pragma unroll
      for (int g = 0; g < 16; ++g) {
        f16x8 hh = *(const f16x8*)(sHg + g * 304 + k0);
        #pragma unroll
        for (int e = 0; e < 8; ++e) acc[g] += wv[e] * (float)hh[e];
      }
    }
    #pragma unroll
    for (int g = 0; g < 16; ++g) {
      float a = acc[g];
      #pragma unroll
      for (int kk = 0; kk < 8; ++kk) a += WT[(HS + kk) * NZ + oo] * s_hd2[g][kk];
      a += ismu ? bmu[oo] : blv[oo];
      out[(ismu ? 0 : BSZ * NZ) + s_gi[g] * NZ + oo] = a;
    }
  }
}

extern "C" void kernel_launch(void* const* d_in, const int* in_sizes, int n_in,
                              void* d_out, int out_size, void* d_ws, size_t ws_size,
                              hipStream_t stream) {
  const int*   node_type = (const int*)d_in[0];
  const int*   pos       = (const int*)d_in[1];
  const int*   adj       = (const int*)d_in[2];
  const int*   vcount    = (const int*)d_in[3];
  const float* rin       = (const float*)d_in[4];
  const float* cin       = (const float*)d_in[5];
  const float* gmin      = (const float*)d_in[6];
  const float* Wih       = (const float*)d_in[7];
  const float* Whh       = (const float*)d_in[8];
  const float* b_ih      = (const float*)d_in[9];
  const float* b_hh      = (const float*)d_in[10];
  const float* Wg        = (const float*)d_in[11];
  const float* bg        = (const float*)d_in[12];
  const float* Wm        = (const float*)d_in[13];
  const float* W1        = (const float*)d_in[14];
  const float* b1        = (const float*)d_in[15];
  const float* W2        = (const float*)d_in[16];
  const float* b2        = (const float*)d_in[17];
  const float* Wmu       = (const float*)d_in[18];
  const float* bmu       = (const float*)d_in[19];
  const float* Wlv       = (const float*)d_in[20];
  const float* blv       = (const float*)d_in[21];

  // ws layout (bytes, all 16B-aligned)
  char* wsb = (char*)d_ws;
  unsigned short* B1 = (unsigned short*)wsb;              // 642,048 B
  unsigned short* B2 = (unsigned short*)(wsb + 642048);   // 389,120 B
  float* WnX  = (float*)(wsb + 1031168);                  // 44,800 B
  float* bn   = (float*)(wsb + 1075968);                  // 1,280 B
  float* WmuT = (float*)(wsb + 1077248);                  // 69,216 B
  float* WlvT = (float*)(wsb + 1146464);                  // 69,216 B
  int*   order = (int*)(wsb + 1215680);                   // 16,384 B

  ckt_prep<<<512, 256, 0, stream>>>(Wih, Whh, b_ih, b_hh, Wg, bg, Wm, Wmu, Wlv,
                                    B1, B2, WnX, bn, WmuT, WlvT);
  ckt_sort<<<1, 1024, 0, stream>>>(vcount, order);

  ckt_main<<<NBLK, NTH, 0, stream>>>(node_type, pos, adj, vcount, rin, cin, gmin,
      W1, b1, W2, b2, bmu, blv,
      (const uint4*)B1, (const uint4*)B2, WnX, bn, WmuT, WlvT, order, (float*)d_out);
}

// Round 10
// 167.907 us; speedup vs baseline: 3.2448x; 2.7424x over previous
//
#include <hip/hip_runtime.h>
#include <hip/hip_bf16.h>

// CktGNN encoder via MFMA. R10: R6 structure + named-register depth-4 B
// pipeline + FIXED launch bounds.
// R8/R9 lesson: WRITE_SIZE/block == |B1|+|B2| exactly -> pipeline slots in
// scratch because __launch_bounds__(N, k) clamped the budget to 64 VGPRs
// (hipcc treats 2nd arg as min blocks/CU -> 8 waves/SIMD -> 512/8=64).
// R10: __launch_bounds__(512) ONLY. NTH=512, BT=8, grid=512 snake-sorted,
// LDS ~75KB (2 blocks/CU if VGPR<=128). Depth-4 named-slot prefetch in both
// GEMMs (12 f16x8 in flight for GRU, 8 for gate).
//   GRU ext K=352: [Hin(301) | onehot_t(26) | onehot_p(9) | 1 | pad]
//   gate ext K=320: [H(301) | onehot_p(9) | 1 | pad]

#define HS 301
#define NVT 26
#define MAXPOS 9
#define MAXN 10
#define BSZ 4096
#define VS 310
#define GS 309
#define NZ 56

#define KT1 11          // GRU ext K tiles (K=352)
#define KT2 10          // gate ext K tiles (K=320)
#define NJT 19          // j tiles (ceil(301/16), covers j<304)
#define NB1 (NJT*KT1*3*512)   // f16 count
#define NB2 (NJT*KT2*2*512)   // f16 count

typedef _Float16 f16x8 __attribute__((ext_vector_type(8)));
typedef float f32x4 __attribute__((ext_vector_type(4)));

constexpr int NTH  = 512;    // 8 waves
constexpr int BT   = 8;
constexpr int NBLK = 512;

__device__ __forceinline__ int fragOff(int g, int k) {
  // byte offset of element (row g, dim k) inside an A-fragment buffer
  return ((k >> 5) << 10) + ((((k & 31) >> 3) << 4) + g) * 16 + ((k & 7) << 1);
}
__device__ __forceinline__ float sigm(float x) { return 1.0f / (1.0f + __expf(-x)); }
__device__ __forceinline__ float tanh_fast(float x) {
  float e = __expf(2.0f * x);
  return 1.0f - 2.0f / (e + 1.0f);
}
#define BC(x) __builtin_bit_cast(f16x8, (x))

// ---------------- sort: counting sort graphs by depth n ----------------
__global__ void ckt_sort(const int* __restrict__ vcount, int* __restrict__ order) {
  __shared__ int cnt[12], off[12];
  int tid = threadIdx.x;
  if (tid < 12) cnt[tid] = 0;
  __syncthreads();
  for (int g = tid; g < BSZ; g += 1024) {
    int n = vcount[g]; n = n < 1 ? 1 : (n > MAXN ? MAXN : n);
    atomicAdd(&cnt[n], 1);
  }
  __syncthreads();
  if (tid == 0) {
    int s = 0;
    for (int i = 1; i <= MAXN; ++i) { off[i] = s; s += cnt[i]; }
  }
  __syncthreads();
  for (int g = tid; g < BSZ; g += 1024) {
    int n = vcount[g]; n = n < 1 ? 1 : (n > MAXN ? MAXN : n);
    int p = atomicAdd(&off[n], 1);
    order[p] = g;
  }
}

// ---------------- prep: pack weights into fragment order ----------------
__global__ void ckt_prep(const float* __restrict__ Wih, const float* __restrict__ Whh,
                         const float* __restrict__ b_ih, const float* __restrict__ b_hh,
                         const float* __restrict__ Wg,  const float* __restrict__ bg,
                         const float* __restrict__ Wm,
                         const float* __restrict__ Wmu, const float* __restrict__ Wlv,
                         unsigned short* __restrict__ B1, unsigned short* __restrict__ B2,
                         float* __restrict__ WnX, float* __restrict__ bn,
                         float* __restrict__ WmuT, float* __restrict__ WlvT)
{
  int i0 = blockIdx.x * blockDim.x + threadIdx.x;
  int str = gridDim.x * blockDim.x;
  // B1: [jt][kt][g3][lane][ii]
  for (int i = i0; i < NB1; i += str) {
    int ii = i & 7, lane = (i >> 3) & 63;
    int r = i >> 9;
    int g3 = r % 3; r /= 3;
    int kt = r % KT1; int jt = r / KT1;
    int j = jt * 16 + (lane & 15);
    int k = kt * 32 + ((lane >> 4) << 3) + ii;
    float val = 0.f;
    if (j < HS) {
      int row = g3 * HS + j;
      if (k < HS) val = Whh[row * HS + k];
      else if (k == 336) val = (g3 < 2) ? (b_ih[row] + b_hh[row]) : b_hh[row];
      else if (g3 < 2) {
        if (k < 327)      val = Wih[row * 35 + (k - 301)];
        else if (k < 336) val = Wih[row * 35 + 26 + (k - 327)];
      }
    }
    B1[i] = __builtin_bit_cast(unsigned short, (_Float16)val);
  }
  // B2: [jt][kt][gm][lane][ii]
  for (int i = i0; i < NB2; i += str) {
    int ii = i & 7, lane = (i >> 3) & 63;
    int r = i >> 9;
    int gm = r % 2; r /= 2;
    int kt = r % KT2; int jt = r / KT2;
    int j = jt * 16 + (lane & 15);
    int k = kt * 32 + ((lane >> 4) << 3) + ii;
    float val = 0.f;
    if (j < HS) {
      const float* W = gm ? Wm : Wg;
      if (k < HS)       val = W[j * VS + k];
      else if (k < 310) val = W[j * VS + HS + (k - 301)];
      else if (k == 310) val = gm ? 0.f : bg[j];
    }
    B2[i] = __builtin_bit_cast(unsigned short, (_Float16)val);
  }
  for (int i = i0; i < 35 * 320; i += str) {
    int x = i / 320, j = i % 320;
    WnX[i] = (j < HS) ? Wih[(2 * HS + j) * 35 + x] : 0.f;
  }
  for (int i = i0; i < 320; i += str) bn[i] = (i < HS) ? b_ih[2 * HS + i] : 0.f;
  for (int i = i0; i < GS * NZ; i += str) {
    int k = i / NZ, o = i % NZ;
    WmuT[i] = Wmu[o * GS + k];
    WlvT[i] = Wlv[o * GS + k];
  }
}

// ---------------- main ----------------
__global__ __launch_bounds__(NTH) void ckt_main(
    const int* __restrict__ node_type, const int* __restrict__ pos,
    const int* __restrict__ adj, const int* __restrict__ vcount,
    const float* __restrict__ rin, const float* __restrict__ cin,
    const float* __restrict__ gmin,
    const float* __restrict__ W1, const float* __restrict__ b1,
    const float* __restrict__ W2, const float* __restrict__ b2,
    const float* __restrict__ bmu, const float* __restrict__ blv,
    const uint4* __restrict__ B1, const uint4* __restrict__ B2,
    const float* __restrict__ WnX, const float* __restrict__ bnG,
    const float* __restrict__ WmuT, const float* __restrict__ WlvT,
    const int* __restrict__ order,
    float* __restrict__ out)
{
  __shared__ __align__(16) _Float16 sGhist[9 * 8 * 304]; // gated history, 43.8 KB
  __shared__ __align__(16) char sAf1[KT1 * 1024];        // GRU A-frags, 11 KB
  __shared__ __align__(16) char sAf2[KT2 * 1024];        // gate A-frags, 10 KB
  __shared__ __align__(16) _Float16 sHg[8 * 304];        // graph state, 4.75 KB
  __shared__ float sBn[320];
  __shared__ int s_gi[8];
  __shared__ int s_t[160], s_p[160], s_n[16];
  __shared__ unsigned s_am[160];
  __shared__ int s_nmax;
  __shared__ float s_df[8][28];
  __shared__ float s_hd[8][16];
  __shared__ float s_hd2[8][8];

  const int tid  = threadIdx.x;
  const int grp  = (blockIdx.x < 256) ? (int)blockIdx.x : 767 - (int)blockIdx.x;
  const int b0   = grp * BT;
  const int w    = tid >> 6;          // 0..7
  const int lane = tid & 63;

  if (tid < 8) s_gi[tid] = order[b0 + tid];
  __syncthreads();
  if (tid < 16) {
    int n = 1;
    if (tid < 8) { n = vcount[s_gi[tid]]; n = n < 1 ? 1 : (n > MAXN ? MAXN : n); }
    s_n[tid] = n;
  }
  if (tid < 8) {   // zero the f16 pad of sHg (read as f16x8 in heads)
    sHg[tid * 304 + 301] = (_Float16)0.f;
    sHg[tid * 304 + 302] = (_Float16)0.f;
    sHg[tid * 304 + 303] = (_Float16)0.f;
  }
  if (tid < 160) {
    int g = tid / 10, vv = tid % 10;
    int t = 0, p = 0;
    if (g < 8) {
      t = node_type[s_gi[g] * MAXN + vv];
      p = pos[s_gi[g] * MAXN + vv];
    }
    s_t[tid] = t; s_p[tid] = p;
  }
  if (tid < 320) sBn[tid] = bnG[tid];
  __syncthreads();
  if (tid < 160) {
    int g = tid / 10, vv = tid % 10;
    unsigned m = 0;
    if (g < 8 && vv < s_n[g]) {
      for (int u = 0; u < vv; ++u)
        if (adj[s_gi[g] * 100 + u * 10 + vv]) m |= (1u << u);
    }
    s_am[tid] = m;
  }
  if (tid == 0) {
    int mx = 1;
    for (int g = 0; g < 8; ++g) mx = max(mx, s_n[g]);
    s_nmax = mx;
  }
  __syncthreads();
  const int nmax = s_nmax;

  const int lq4 = (lane >> 4) << 2;   // base graph row of this lane's D rows
  const int jc  = lane & 15;          // column-within-tile

  for (int v = 0; v < nmax; ++v) {
    // ---------- phase A: build GRU A-frags (Hin + one-hots) ----------
    for (int c = tid; c < KT1 * 64; c += NTH) {
      int kt = c >> 6, ln = c & 63, g = ln & 15;
      int k0 = (kt << 5) + ((ln >> 4) << 3);
      unsigned am = s_am[g * 10 + v];   // pads (g>=8) have am=0
      int gg = g & 7;                   // pads alias rows 0-7; masked to 0 anyway
      f16x8 pk;
      if (k0 + 8 <= HS) {               // pure Hin chunk
        float a0 = 0.f, a1 = 0.f, a2 = 0.f, a3 = 0.f;
        float a4 = 0.f, a5 = 0.f, a6 = 0.f, a7 = 0.f;
        for (int u = 0; u < v; ++u) {
          float mf = (float)((am >> u) & 1u);
          f16x8 hh = *(const f16x8*)(sGhist + (u * 8 + gg) * 304 + k0);
          a0 += mf * (float)hh[0]; a1 += mf * (float)hh[1];
          a2 += mf * (float)hh[2]; a3 += mf * (float)hh[3];
          a4 += mf * (float)hh[4]; a5 += mf * (float)hh[5];
          a6 += mf * (float)hh[6]; a7 += mf * (float)hh[7];
        }
        pk[0] = (_Float16)a0; pk[1] = (_Float16)a1;
        pk[2] = (_Float16)a2; pk[3] = (_Float16)a3;
        pk[4] = (_Float16)a4; pk[5] = (_Float16)a5;
        pk[6] = (_Float16)a6; pk[7] = (_Float16)a7;
      } else {                          // boundary / one-hot region
        int t = s_t[g * 10 + v], p = s_p[g * 10 + v];
        #pragma unroll
        for (int e = 0; e < 8; ++e) {
          int k = k0 + e;
          float x = 0.f;
          if (k < HS) {
            for (int u = 0; u < v; ++u) {
              float mf = (float)((am >> u) & 1u);
              x += mf * (float)sGhist[(u * 8 + gg) * 304 + k];
            }
          } else if (k < 327) x = (k - 301 == t) ? 1.f : 0.f;
          else if (k < 336)   x = (k - 327 == p) ? 1.f : 0.f;
          else if (k == 336)  x = 1.f;
          pk[e] = (_Float16)x;
        }
      }
      *(f16x8*)(sAf1 + c * 16) = pk;
    }
    // gate A-frag one-hot region (k=301..319), 16 rows x 19 k (strided-safe)
    for (int i = tid; i < 16 * 19; i += NTH) {
      int g = i / 19, kk = 301 + i % 19;
      float val = (kk < 310) ? ((kk - 301 == s_p[g * 10 + v]) ? 1.f : 0.f)
                             : ((kk == 310) ? 1.f : 0.f);
      *(_Float16*)(sAf2 + fragOff(g, kk)) = (_Float16)val;
    }
    __syncthreads();

    // ---------- GRU GEMM, jt in {w, w+8, w+16}: depth-4 named pipeline ----------
#define LB1(P0, P1, P2, KT) \
      P0 = BC(Bp[((KT) * 3 + 0) * 64]); \
      P1 = BC(Bp[((KT) * 3 + 1) * 64]); \
      P2 = BC(Bp[((KT) * 3 + 2) * 64]);
#define ST1(P0, P1, P2, KT, KTN) { \
      f16x8 av = *(const f16x8*)(sAf1 + (KT) * 1024 + lane * 16); \
      f16x8 c0 = P0, c1 = P1, c2 = P2; \
      LB1(P0, P1, P2, KTN) \
      a0 = __builtin_amdgcn_mfma_f32_16x16x32_f16(av, c0, a0, 0, 0, 0); \
      a1 = __builtin_amdgcn_mfma_f32_16x16x32_f16(av, c1, a1, 0, 0, 0); \
      a2 = __builtin_amdgcn_mfma_f32_16x16x32_f16(av, c2, a2, 0, 0, 0); }
#define ST1E(P0, P1, P2, KT) { \
      f16x8 av = *(const f16x8*)(sAf1 + (KT) * 1024 + lane * 16); \
      a0 = __builtin_amdgcn_mfma_f32_16x16x32_f16(av, P0, a0, 0, 0, 0); \
      a1 = __builtin_amdgcn_mfma_f32_16x16x32_f16(av, P1, a1, 0, 0, 0); \
      a2 = __builtin_amdgcn_mfma_f32_16x16x32_f16(av, P2, a2, 0, 0, 0); }
    for (int jj = w; jj < NJT; jj += 8) {
      const uint4* Bp = B1 + (size_t)jj * (KT1 * 3 * 64) + lane;
      f16x8 p00, p01, p02, p10, p11, p12, p20, p21, p22, p30, p31, p32;
      LB1(p00, p01, p02, 0) LB1(p10, p11, p12, 1)
      LB1(p20, p21, p22, 2) LB1(p30, p31, p32, 3)
      f32x4 a0 = {0.f, 0.f, 0.f, 0.f}, a1 = a0, a2 = a0;
      ST1(p00, p01, p02, 0, 4) ST1(p10, p11, p12, 1, 5)
      ST1(p20, p21, p22, 2, 6) ST1(p30, p31, p32, 3, 7)
      ST1(p00, p01, p02, 4, 8) ST1(p10, p11, p12, 5, 9)
      ST1(p20, p21, p22, 6, 10)
      ST1E(p30, p31, p32, 7) ST1E(p00, p01, p02, 8)
      ST1E(p10, p11, p12, 9) ST1E(p20, p21, p22, 10)
      // epilogue (D: row=graph=(lane>>4)*4+q, col=j=lane&15)
      int j = jj * 16 + jc;
      bool jv = j < HS;
      #pragma unroll
      for (int q = 0; q < 4; ++q) {
        int g = lq4 + q;
        float inn = 0.f;
        if (jv) {
          int t = s_t[g * 10 + v], p = s_p[g * 10 + v];
          inn = sBn[j] + WnX[t * 320 + j] + WnX[(26 + p) * 320 + j];
        }
        float rg = sigm(a0[q]);
        float zg = sigm(a1[q]);
        float ng = tanh_fast(inn + rg * a2[q]);
        float hinv = jv ? (float)*(const _Float16*)(sAf1 + fragOff(g, j)) : 0.f;
        float hv = (1.f - zg) * ng + zg * hinv;
        float hval = (v < s_n[g]) ? hv : 0.f;
        if (jv) {
          *(_Float16*)(sAf2 + fragOff(g, j)) = (_Float16)hval;
          if (g < 8 && v == s_n[g] - 1) sHg[g * 304 + j] = (_Float16)hv;
        }
      }
    }
#undef ST1
#undef ST1E
#undef LB1
    __syncthreads();

    // ---------- gate/mapper GEMM: depth-4 named pipeline ----------
    if (v < nmax - 1) {
#define LB2(P0, P1, KT) \
        P0 = BC(Bp[((KT) * 2 + 0) * 64]); \
        P1 = BC(Bp[((KT) * 2 + 1) * 64]);
#define ST2(P0, P1, KT, KTN) { \
        f16x8 av = *(const f16x8*)(sAf2 + (KT) * 1024 + lane * 16); \
        f16x8 d0 = P0, d1 = P1; \
        LB2(P0, P1, KTN) \
        c0 = __builtin_amdgcn_mfma_f32_16x16x32_f16(av, d0, c0, 0, 0, 0); \
        c1 = __builtin_amdgcn_mfma_f32_16x16x32_f16(av, d1, c1, 0, 0, 0); }
#define ST2E(P0, P1, KT) { \
        f16x8 av = *(const f16x8*)(sAf2 + (KT) * 1024 + lane * 16); \
        c0 = __builtin_amdgcn_mfma_f32_16x16x32_f16(av, P0, c0, 0, 0, 0); \
        c1 = __builtin_amdgcn_mfma_f32_16x16x32_f16(av, P1, c1, 0, 0, 0); }
      for (int jj = w; jj < NJT; jj += 8) {
        const uint4* Bp = B2 + (size_t)jj * (KT2 * 2 * 64) + lane;
        f16x8 q00, q01, q10, q11, q20, q21, q30, q31;
        LB2(q00, q01, 0) LB2(q10, q11, 1) LB2(q20, q21, 2) LB2(q30, q31, 3)
        f32x4 c0 = {0.f, 0.f, 0.f, 0.f}, c1 = c0;
        ST2(q00, q01, 0, 4) ST2(q10, q11, 1, 5) ST2(q20, q21, 2, 6)
        ST2(q30, q31, 3, 7) ST2(q00, q01, 4, 8) ST2(q10, q11, 5, 9)
        ST2E(q20, q21, 6) ST2E(q30, q31, 7) ST2E(q00, q01, 8) ST2E(q10, q11, 9)
        int j = jj * 16 + jc;
        if (j < HS) {
          #pragma unroll
          for (int q = 0; q < 4; ++q) {
            int g = lq4 + q;
            if (g < 8) {
              float gg = sigm(c0[q]);
              sGhist[(v * 8 + g) * 304 + j] = (_Float16)(gg * c1[q]);
            }
          }
        }
      }
#undef ST2
#undef ST2E
#undef LB2
    }
    __syncthreads();
  }

  // ---------- df feature ----------
  if (tid < 8) {
    int g = tid;
    #pragma unroll
    for (int i2 = 0; i2 < 27; ++i2) s_df[g][i2] = 0.f;
    int n = s_n[g];
    int gi = s_gi[g];
    for (int vv = 0; vv < n; ++vv) {
      int p = s_p[g * 10 + vv];
      int base = gi * MAXN + vv;
      s_df[g][3 * p]     = rin[base];
      s_df[g][3 * p + 1] = cin[base];
      s_df[g][3 * p + 2] = gmin[base];
    }
  }
  __syncthreads();

  // ---------- df_enc ----------
  if (tid < 128) {
    int bb = tid >> 4, o = tid & 15;   // 8x16
    float a = b1[o];
    #pragma unroll
    for (int k = 0; k < 27; ++k) a = fmaf(W1[o * 27 + k], s_df[bb][k], a);
    s_hd[bb][o] = fmaxf(a, 0.f);
  }
  __syncthreads();
  if (tid < 64) {
    int bb = tid >> 3, o = tid & 7;    // 8x8
    float a = b2[o];
    #pragma unroll
    for (int k = 0; k < 16; ++k) a = fmaf(W2[o * 16 + k], s_hd[bb][k], a);
    s_hd2[bb][o] = a;
  }
  __syncthreads();

  // ---------- heads ----------
  if (tid < 2 * NZ) {
    bool ismu = tid < NZ;
    int oo = ismu ? tid : tid - NZ;
    const float* WT = ismu ? WmuT : WlvT;
    float acc[8];
    #pragma unroll
    for (int g = 0; g < 8; ++g) acc[g] = 0.f;
    for (int k0 = 0; k0 < 304; k0 += 8) {
      float wv[8];
      #pragma unroll
      for (int e = 0; e < 8; ++e) {
        int k = k0 + e;
        wv[e] = (k < HS) ? WT[k * NZ + oo] : 0.f;
      }
      #pragma unroll
      for (int g = 0; g < 8; ++g) {
        f16x8 hh = *(const f16x8*)(sHg + g * 304 + k0);
        #pragma unroll
        for (int e = 0; e < 8; ++e) acc[g] += wv[e] * (float)hh[e];
      }
    }
    #pragma unroll
    for (int g = 0; g < 8; ++g) {
      float a = acc[g];
      #pragma unroll
      for (int kk = 0; kk < 8; ++kk) a += WT[(HS + kk) * NZ + oo] * s_hd2[g][kk];
      a += ismu ? bmu[oo] : blv[oo];
      out[(ismu ? 0 : BSZ * NZ) + s_gi[g] * NZ + oo] = a;
    }
  }
}

extern "C" void kernel_launch(void* const* d_in, const int* in_sizes, int n_in,
                              void* d_out, int out_size, void* d_ws, size_t ws_size,
                              hipStream_t stream) {
  const int*   node_type = (const int*)d_in[0];
  const int*   pos       = (const int*)d_in[1];
  const int*   adj       = (const int*)d_in[2];
  const int*   vcount    = (const int*)d_in[3];
  const float* rin       = (const float*)d_in[4];
  const float* cin       = (const float*)d_in[5];
  const float* gmin      = (const float*)d_in[6];
  const float* Wih       = (const float*)d_in[7];
  const float* Whh       = (const float*)d_in[8];
  const float* b_ih      = (const float*)d_in[9];
  const float* b_hh      = (const float*)d_in[10];
  const float* Wg        = (const float*)d_in[11];
  const float* bg        = (const float*)d_in[12];
  const float* Wm        = (const float*)d_in[13];
  const float* W1        = (const float*)d_in[14];
  const float* b1        = (const float*)d_in[15];
  const float* W2        = (const float*)d_in[16];
  const float* b2        = (const float*)d_in[17];
  const float* Wmu       = (const float*)d_in[18];
  const float* bmu       = (const float*)d_in[19];
  const float* Wlv       = (const float*)d_in[20];
  const float* blv       = (const float*)d_in[21];

  // ws layout (bytes, all 16B-aligned)
  char* wsb = (char*)d_ws;
  unsigned short* B1 = (unsigned short*)wsb;              // 642,048 B
  unsigned short* B2 = (unsigned short*)(wsb + 642048);   // 389,120 B
  float* WnX  = (float*)(wsb + 1031168);                  // 44,800 B
  float* bn   = (float*)(wsb + 1075968);                  // 1,280 B
  float* WmuT = (float*)(wsb + 1077248);                  // 69,216 B
  float* WlvT = (float*)(wsb + 1146464);                  // 69,216 B
  int*   order = (int*)(wsb + 1215680);                   // 16,384 B

  ckt_prep<<<512, 256, 0, stream>>>(Wih, Whh, b_ih, b_hh, Wg, bg, Wm, Wmu, Wlv,
                                    B1, B2, WnX, bn, WmuT, WlvT);
  ckt_sort<<<1, 1024, 0, stream>>>(vcount, order);

  ckt_main<<<NBLK, NTH, 0, stream>>>(node_type, pos, adj, vcount, rin, cin, gmin,
      W1, b1, W2, b2, bmu, blv,
      (const uint4*)B1, (const uint4*)B2, WnX, bn, WmuT, WlvT, order, (float*)d_out);
}

// Round 11
// 162.379 us; speedup vs baseline: 3.3553x; 1.0340x over previous
//
#include <hip/hip_runtime.h>
#include <hip/hip_bf16.h>

// CktGNN encoder via MFMA. R11: full M=16 utilization (BT=16) to halve
// per-graph B traffic — R10 was per-CU L2-BW-bound streaming B for only
// 8 real graphs on 16-row MFMA tiles.
// grid=256 (1 block/CU), NTH=1024 (16 waves; waves 0-2 double-tile),
// sorted homogeneous groups, named depth-4 B pipeline (R10), and
// __launch_bounds__(1024) ONLY (R10 lesson: a min-occupancy 2nd arg
// clamps VGPRs to 64 and spills the pipeline).
//   GRU ext K=352: [Hin(301) | onehot_t(26) | onehot_p(9) | 1 | pad]
//   gate ext K=320: [H(301) | onehot_p(9) | 1 | pad]

#define HS 301
#define NVT 26
#define MAXPOS 9
#define MAXN 10
#define BSZ 4096
#define VS 310
#define GS 309
#define NZ 56

#define KT1 11          // GRU ext K tiles (K=352)
#define KT2 10          // gate ext K tiles (K=320)
#define NJT 19          // j tiles (ceil(301/16), covers j<304)
#define NB1 (NJT*KT1*3*512)   // f16 count
#define NB2 (NJT*KT2*2*512)   // f16 count

typedef _Float16 f16x8 __attribute__((ext_vector_type(8)));
typedef float f32x4 __attribute__((ext_vector_type(4)));

constexpr int NTH  = 1024;   // 16 waves
constexpr int BT   = 16;
constexpr int NBLK = 256;

__device__ __forceinline__ int fragOff(int g, int k) {
  // byte offset of element (row g, dim k) inside an A-fragment buffer
  return ((k >> 5) << 10) + ((((k & 31) >> 3) << 4) + g) * 16 + ((k & 7) << 1);
}
__device__ __forceinline__ float sigm(float x) { return 1.0f / (1.0f + __expf(-x)); }
__device__ __forceinline__ float tanh_fast(float x) {
  float e = __expf(2.0f * x);
  return 1.0f - 2.0f / (e + 1.0f);
}
#define BC(x) __builtin_bit_cast(f16x8, (x))

// ---------------- sort: counting sort graphs by depth n ----------------
__global__ void ckt_sort(const int* __restrict__ vcount, int* __restrict__ order) {
  __shared__ int cnt[12], off[12];
  int tid = threadIdx.x;
  if (tid < 12) cnt[tid] = 0;
  __syncthreads();
  for (int g = tid; g < BSZ; g += 1024) {
    int n = vcount[g]; n = n < 1 ? 1 : (n > MAXN ? MAXN : n);
    atomicAdd(&cnt[n], 1);
  }
  __syncthreads();
  if (tid == 0) {
    int s = 0;
    for (int i = 1; i <= MAXN; ++i) { off[i] = s; s += cnt[i]; }
  }
  __syncthreads();
  for (int g = tid; g < BSZ; g += 1024) {
    int n = vcount[g]; n = n < 1 ? 1 : (n > MAXN ? MAXN : n);
    int p = atomicAdd(&off[n], 1);
    order[p] = g;
  }
}

// ---------------- prep: pack weights into fragment order ----------------
__global__ void ckt_prep(const float* __restrict__ Wih, const float* __restrict__ Whh,
                         const float* __restrict__ b_ih, const float* __restrict__ b_hh,
                         const float* __restrict__ Wg,  const float* __restrict__ bg,
                         const float* __restrict__ Wm,
                         const float* __restrict__ Wmu, const float* __restrict__ Wlv,
                         unsigned short* __restrict__ B1, unsigned short* __restrict__ B2,
                         float* __restrict__ WnX, float* __restrict__ bn,
                         float* __restrict__ WmuT, float* __restrict__ WlvT)
{
  int i0 = blockIdx.x * blockDim.x + threadIdx.x;
  int str = gridDim.x * blockDim.x;
  // B1: [jt][kt][g3][lane][ii]
  for (int i = i0; i < NB1; i += str) {
    int ii = i & 7, lane = (i >> 3) & 63;
    int r = i >> 9;
    int g3 = r % 3; r /= 3;
    int kt = r % KT1; int jt = r / KT1;
    int j = jt * 16 + (lane & 15);
    int k = kt * 32 + ((lane >> 4) << 3) + ii;
    float val = 0.f;
    if (j < HS) {
      int row = g3 * HS + j;
      if (k < HS) val = Whh[row * HS + k];
      else if (k == 336) val = (g3 < 2) ? (b_ih[row] + b_hh[row]) : b_hh[row];
      else if (g3 < 2) {
        if (k < 327)      val = Wih[row * 35 + (k - 301)];
        else if (k < 336) val = Wih[row * 35 + 26 + (k - 327)];
      }
    }
    B1[i] = __builtin_bit_cast(unsigned short, (_Float16)val);
  }
  // B2: [jt][kt][gm][lane][ii]
  for (int i = i0; i < NB2; i += str) {
    int ii = i & 7, lane = (i >> 3) & 63;
    int r = i >> 9;
    int gm = r % 2; r /= 2;
    int kt = r % KT2; int jt = r / KT2;
    int j = jt * 16 + (lane & 15);
    int k = kt * 32 + ((lane >> 4) << 3) + ii;
    float val = 0.f;
    if (j < HS) {
      const float* W = gm ? Wm : Wg;
      if (k < HS)       val = W[j * VS + k];
      else if (k < 310) val = W[j * VS + HS + (k - 301)];
      else if (k == 310) val = gm ? 0.f : bg[j];
    }
    B2[i] = __builtin_bit_cast(unsigned short, (_Float16)val);
  }
  for (int i = i0; i < 35 * 320; i += str) {
    int x = i / 320, j = i % 320;
    WnX[i] = (j < HS) ? Wih[(2 * HS + j) * 35 + x] : 0.f;
  }
  for (int i = i0; i < 320; i += str) bn[i] = (i < HS) ? b_ih[2 * HS + i] : 0.f;
  for (int i = i0; i < GS * NZ; i += str) {
    int k = i / NZ, o = i % NZ;
    WmuT[i] = Wmu[o * GS + k];
    WlvT[i] = Wlv[o * GS + k];
  }
}

// ---------------- main ----------------
__global__ __launch_bounds__(NTH) void ckt_main(
    const int* __restrict__ node_type, const int* __restrict__ pos,
    const int* __restrict__ adj, const int* __restrict__ vcount,
    const float* __restrict__ rin, const float* __restrict__ cin,
    const float* __restrict__ gmin,
    const float* __restrict__ W1, const float* __restrict__ b1,
    const float* __restrict__ W2, const float* __restrict__ b2,
    const float* __restrict__ bmu, const float* __restrict__ blv,
    const uint4* __restrict__ B1, const uint4* __restrict__ B2,
    const float* __restrict__ WnX, const float* __restrict__ bnG,
    const float* __restrict__ WmuT, const float* __restrict__ WlvT,
    const int* __restrict__ order,
    float* __restrict__ out)
{
  __shared__ __align__(16) _Float16 sGhist[9 * 16 * 304]; // gated history, 87.5 KB
  __shared__ __align__(16) char sAf1[KT1 * 1024];         // GRU A-frags, 11 KB
  __shared__ __align__(16) char sAf2[KT2 * 1024];         // gate A-frags, 10 KB
  __shared__ __align__(16) _Float16 sHg[16 * 304];        // graph state, 9.5 KB
  __shared__ float sBn[320];
  __shared__ int s_gi[16];
  __shared__ int s_t[160], s_p[160], s_n[16];
  __shared__ unsigned s_am[160];
  __shared__ int s_nmax;
  __shared__ float s_df[16][28];
  __shared__ float s_hd[16][16];
  __shared__ float s_hd2[16][8];

  const int tid  = threadIdx.x;
  const int b0   = blockIdx.x * BT;
  const int w    = tid >> 6;          // 0..15
  const int lane = tid & 63;

  if (tid < 16) s_gi[tid] = order[b0 + tid];
  __syncthreads();
  if (tid < 16) {
    int n = vcount[s_gi[tid]];
    s_n[tid] = n < 1 ? 1 : (n > MAXN ? MAXN : n);
    sHg[tid * 304 + 301] = (_Float16)0.f;   // zero f16 pad (heads read f16x8)
    sHg[tid * 304 + 302] = (_Float16)0.f;
    sHg[tid * 304 + 303] = (_Float16)0.f;
  }
  if (tid < 160) {
    int g = tid / 10, vv = tid % 10;
    s_t[tid] = node_type[s_gi[g] * MAXN + vv];
    s_p[tid] = pos[s_gi[g] * MAXN + vv];
  }
  if (tid < 320) sBn[tid] = bnG[tid];
  __syncthreads();
  if (tid < 160) {
    int g = tid / 10, vv = tid % 10;
    unsigned m = 0;
    if (vv < s_n[g]) {
      for (int u = 0; u < vv; ++u)
        if (adj[s_gi[g] * 100 + u * 10 + vv]) m |= (1u << u);
    }
    s_am[tid] = m;
  }
  if (tid == 0) {
    int mx = 1;
    for (int g = 0; g < 16; ++g) mx = max(mx, s_n[g]);
    s_nmax = mx;
  }
  __syncthreads();
  const int nmax = s_nmax;

  const int lq4 = (lane >> 4) << 2;   // base graph row of this lane's D rows
  const int jc  = lane & 15;          // column-within-tile

  for (int v = 0; v < nmax; ++v) {
    // ---------- phase A: build GRU A-frags + gate one-hot region ----------
    if (tid < KT1 * 64) {              // 704 threads
      int c = tid;
      int kt = c >> 6, ln = c & 63, g = ln & 15;
      int k0 = (kt << 5) + ((ln >> 4) << 3);
      unsigned am = s_am[g * 10 + v];
      f16x8 pk;
      if (k0 + 8 <= HS) {               // pure Hin chunk
        float a0 = 0.f, a1 = 0.f, a2 = 0.f, a3 = 0.f;
        float a4 = 0.f, a5 = 0.f, a6 = 0.f, a7 = 0.f;
        for (int u = 0; u < v; ++u) {
          float mf = (float)((am >> u) & 1u);
          f16x8 hh = *(const f16x8*)(sGhist + (u * 16 + g) * 304 + k0);
          a0 += mf * (float)hh[0]; a1 += mf * (float)hh[1];
          a2 += mf * (float)hh[2]; a3 += mf * (float)hh[3];
          a4 += mf * (float)hh[4]; a5 += mf * (float)hh[5];
          a6 += mf * (float)hh[6]; a7 += mf * (float)hh[7];
        }
        pk[0] = (_Float16)a0; pk[1] = (_Float16)a1;
        pk[2] = (_Float16)a2; pk[3] = (_Float16)a3;
        pk[4] = (_Float16)a4; pk[5] = (_Float16)a5;
        pk[6] = (_Float16)a6; pk[7] = (_Float16)a7;
      } else {                          // boundary / one-hot region
        int t = s_t[g * 10 + v], p = s_p[g * 10 + v];
        #pragma unroll
        for (int e = 0; e < 8; ++e) {
          int k = k0 + e;
          float x = 0.f;
          if (k < HS) {
            for (int u = 0; u < v; ++u) {
              float mf = (float)((am >> u) & 1u);
              x += mf * (float)sGhist[(u * 16 + g) * 304 + k];
            }
          } else if (k < 327) x = (k - 301 == t) ? 1.f : 0.f;
          else if (k < 336)   x = (k - 327 == p) ? 1.f : 0.f;
          else if (k == 336)  x = 1.f;
          pk[e] = (_Float16)x;
        }
      }
      *(f16x8*)(sAf1 + c * 16) = pk;
    } else if (tid - KT1 * 64 < 16 * 19) {  // gate A-frag one-hots k=301..319
      int i = tid - KT1 * 64;
      int g = i / 19, kk = 301 + i % 19;
      float val = (kk < 310) ? ((kk - 301 == s_p[g * 10 + v]) ? 1.f : 0.f)
                             : ((kk == 310) ? 1.f : 0.f);
      *(_Float16*)(sAf2 + fragOff(g, kk)) = (_Float16)val;
    }
    __syncthreads();

    // ---------- GRU GEMM, jt in {w, w+16 (w<3)}: depth-4 named pipeline ----------
#define LB1(P0, P1, P2, KT) \
      P0 = BC(Bp[((KT) * 3 + 0) * 64]); \
      P1 = BC(Bp[((KT) * 3 + 1) * 64]); \
      P2 = BC(Bp[((KT) * 3 + 2) * 64]);
#define ST1(P0, P1, P2, KT, KTN) { \
      f16x8 av = *(const f16x8*)(sAf1 + (KT) * 1024 + lane * 16); \
      f16x8 c0 = P0, c1 = P1, c2 = P2; \
      LB1(P0, P1, P2, KTN) \
      a0 = __builtin_amdgcn_mfma_f32_16x16x32_f16(av, c0, a0, 0, 0, 0); \
      a1 = __builtin_amdgcn_mfma_f32_16x16x32_f16(av, c1, a1, 0, 0, 0); \
      a2 = __builtin_amdgcn_mfma_f32_16x16x32_f16(av, c2, a2, 0, 0, 0); }
#define ST1E(P0, P1, P2, KT) { \
      f16x8 av = *(const f16x8*)(sAf1 + (KT) * 1024 + lane * 16); \
      a0 = __builtin_amdgcn_mfma_f32_16x16x32_f16(av, P0, a0, 0, 0, 0); \
      a1 = __builtin_amdgcn_mfma_f32_16x16x32_f16(av, P1, a1, 0, 0, 0); \
      a2 = __builtin_amdgcn_mfma_f32_16x16x32_f16(av, P2, a2, 0, 0, 0); }
    for (int jj = w; jj < NJT; jj += 16) {
      const uint4* Bp = B1 + (size_t)jj * (KT1 * 3 * 64) + lane;
      f16x8 p00, p01, p02, p10, p11, p12, p20, p21, p22, p30, p31, p32;
      LB1(p00, p01, p02, 0) LB1(p10, p11, p12, 1)
      LB1(p20, p21, p22, 2) LB1(p30, p31, p32, 3)
      f32x4 a0 = {0.f, 0.f, 0.f, 0.f}, a1 = a0, a2 = a0;
      ST1(p00, p01, p02, 0, 4) ST1(p10, p11, p12, 1, 5)
      ST1(p20, p21, p22, 2, 6) ST1(p30, p31, p32, 3, 7)
      ST1(p00, p01, p02, 4, 8) ST1(p10, p11, p12, 5, 9)
      ST1(p20, p21, p22, 6, 10)
      ST1E(p30, p31, p32, 7) ST1E(p00, p01, p02, 8)
      ST1E(p10, p11, p12, 9) ST1E(p20, p21, p22, 10)
      // epilogue (D: row=graph=(lane>>4)*4+q, col=j=lane&15)
      int j = jj * 16 + jc;
      bool jv = j < HS;
      #pragma unroll
      for (int q = 0; q < 4; ++q) {
        int g = lq4 + q;
        float inn = 0.f;
        if (jv) {
          int t = s_t[g * 10 + v], p = s_p[g * 10 + v];
          inn = sBn[j] + WnX[t * 320 + j] + WnX[(26 + p) * 320 + j];
        }
        float rg = sigm(a0[q]);
        float zg = sigm(a1[q]);
        float ng = tanh_fast(inn + rg * a2[q]);
        float hinv = jv ? (float)*(const _Float16*)(sAf1 + fragOff(g, j)) : 0.f;
        float hv = (1.f - zg) * ng + zg * hinv;
        float hval = (v < s_n[g]) ? hv : 0.f;
        if (jv) {
          *(_Float16*)(sAf2 + fragOff(g, j)) = (_Float16)hval;
          if (v == s_n[g] - 1) sHg[g * 304 + j] = (_Float16)hv;
        }
      }
    }
#undef ST1
#undef ST1E
#undef LB1
    __syncthreads();

    // ---------- gate/mapper GEMM: depth-4 named pipeline ----------
    if (v < nmax - 1) {
#define LB2(P0, P1, KT) \
        P0 = BC(Bp[((KT) * 2 + 0) * 64]); \
        P1 = BC(Bp[((KT) * 2 + 1) * 64]);
#define ST2(P0, P1, KT, KTN) { \
        f16x8 av = *(const f16x8*)(sAf2 + (KT) * 1024 + lane * 16); \
        f16x8 d0 = P0, d1 = P1; \
        LB2(P0, P1, KTN) \
        c0 = __builtin_amdgcn_mfma_f32_16x16x32_f16(av, d0, c0, 0, 0, 0); \
        c1 = __builtin_amdgcn_mfma_f32_16x16x32_f16(av, d1, c1, 0, 0, 0); }
#define ST2E(P0, P1, KT) { \
        f16x8 av = *(const f16x8*)(sAf2 + (KT) * 1024 + lane * 16); \
        c0 = __builtin_amdgcn_mfma_f32_16x16x32_f16(av, P0, c0, 0, 0, 0); \
        c1 = __builtin_amdgcn_mfma_f32_16x16x32_f16(av, P1, c1, 0, 0, 0); }
      for (int jj = w; jj < NJT; jj += 16) {
        const uint4* Bp = B2 + (size_t)jj * (KT2 * 2 * 64) + lane;
        f16x8 q00, q01, q10, q11, q20, q21, q30, q31;
        LB2(q00, q01, 0) LB2(q10, q11, 1) LB2(q20, q21, 2) LB2(q30, q31, 3)
        f32x4 c0 = {0.f, 0.f, 0.f, 0.f}, c1 = c0;
        ST2(q00, q01, 0, 4) ST2(q10, q11, 1, 5) ST2(q20, q21, 2, 6)
        ST2(q30, q31, 3, 7) ST2(q00, q01, 4, 8) ST2(q10, q11, 5, 9)
        ST2E(q20, q21, 6) ST2E(q30, q31, 7) ST2E(q00, q01, 8) ST2E(q10, q11, 9)
        int j = jj * 16 + jc;
        if (j < HS) {
          #pragma unroll
          for (int q = 0; q < 4; ++q) {
            int g = lq4 + q;
            float gg = sigm(c0[q]);
            sGhist[(v * 16 + g) * 304 + j] = (_Float16)(gg * c1[q]);
          }
        }
      }
#undef ST2
#undef ST2E
#undef LB2
    }
    __syncthreads();
  }

  // ---------- df feature ----------
  if (tid < 16) {
    int g = tid;
    #pragma unroll
    for (int i2 = 0; i2 < 27; ++i2) s_df[g][i2] = 0.f;
    int n = s_n[g];
    int gi = s_gi[g];
    for (int vv = 0; vv < n; ++vv) {
      int p = s_p[g * 10 + vv];
      int base = gi * MAXN + vv;
      s_df[g][3 * p]     = rin[base];
      s_df[g][3 * p + 1] = cin[base];
      s_df[g][3 * p + 2] = gmin[base];
    }
  }
  __syncthreads();

  // ---------- df_enc ----------
  if (tid < 256) {
    int bb = tid >> 4, o = tid & 15;   // 16x16
    float a = b1[o];
    #pragma unroll
    for (int k = 0; k < 27; ++k) a = fmaf(W1[o * 27 + k], s_df[bb][k], a);
    s_hd[bb][o] = fmaxf(a, 0.f);
  }
  __syncthreads();
  if (tid < 128) {
    int bb = tid >> 3, o = tid & 7;
    float a = b2[o];
    #pragma unroll
    for (int k = 0; k < 16; ++k) a = fmaf(W2[o * 16 + k], s_hd[bb][k], a);
    s_hd2[bb][o] = a;
  }
  __syncthreads();

  // ---------- heads ----------
  if (tid < 2 * NZ) {
    bool ismu = tid < NZ;
    int oo = ismu ? tid : tid - NZ;
    const float* WT = ismu ? WmuT : WlvT;
    float acc[16];
    #pragma unroll
    for (int g = 0; g < 16; ++g) acc[g] = 0.f;
    for (int k0 = 0; k0 < 304; k0 += 8) {
      float wv[8];
      #pragma unroll
      for (int e = 0; e < 8; ++e) {
        int k = k0 + e;
        wv[e] = (k < HS) ? WT[k * NZ + oo] : 0.f;
      }
      #pragma unroll
      for (int g = 0; g < 16; ++g) {
        f16x8 hh = *(const f16x8*)(sHg + g * 304 + k0);
        #pragma unroll
        for (int e = 0; e < 8; ++e) acc[g] += wv[e] * (float)hh[e];
      }
    }
    #pragma unroll
    for (int g = 0; g < 16; ++g) {
      float a = acc[g];
      #pragma unroll
      for (int kk = 0; kk < 8; ++kk) a += WT[(HS + kk) * NZ + oo] * s_hd2[g][kk];
      a += ismu ? bmu[oo] : blv[oo];
      out[(ismu ? 0 : BSZ * NZ) + s_gi[g] * NZ + oo] = a;
    }
  }
}

extern "C" void kernel_launch(void* const* d_in, const int* in_sizes, int n_in,
                              void* d_out, int out_size, void* d_ws, size_t ws_size,
                              hipStream_t stream) {
  const int*   node_type = (const int*)d_in[0];
  const int*   pos       = (const int*)d_in[1];
  const int*   adj       = (const int*)d_in[2];
  const int*   vcount    = (const int*)d_in[3];
  const float* rin       = (const float*)d_in[4];
  const float* cin       = (const float*)d_in[5];
  const float* gmin      = (const float*)d_in[6];
  const float* Wih       = (const float*)d_in[7];
  const float* Whh       = (const float*)d_in[8];
  const float* b_ih      = (const float*)d_in[9];
  const float* b_hh      = (const float*)d_in[10];
  const float* Wg        = (const float*)d_in[11];
  const float* bg        = (const float*)d_in[12];
  const float* Wm        = (const float*)d_in[13];
  const float* W1        = (const float*)d_in[14];
  const float* b1        = (const float*)d_in[15];
  const float* W2        = (const float*)d_in[16];
  const float* b2        = (const float*)d_in[17];
  const float* Wmu       = (const float*)d_in[18];
  const float* bmu       = (const float*)d_in[19];
  const float* Wlv       = (const float*)d_in[20];
  const float* blv       = (const float*)d_in[21];

  // ws layout (bytes, all 16B-aligned)
  char* wsb = (char*)d_ws;
  unsigned short* B1 = (unsigned short*)wsb;              // 642,048 B
  unsigned short* B2 = (unsigned short*)(wsb + 642048);   // 389,120 B
  float* WnX  = (float*)(wsb + 1031168);                  // 44,800 B
  float* bn   = (float*)(wsb + 1075968);                  // 1,280 B
  float* WmuT = (float*)(wsb + 1077248);                  // 69,216 B
  float* WlvT = (float*)(wsb + 1146464);                  // 69,216 B
  int*   order = (int*)(wsb + 1215680);                   // 16,384 B

  ckt_prep<<<512, 256, 0, stream>>>(Wih, Whh, b_ih, b_hh, Wg, bg, Wm, Wmu, Wlv,
                                    B1, B2, WnX, bn, WmuT, WlvT);
  ckt_sort<<<1, 1024, 0, stream>>>(vcount, order);

  ckt_main<<<NBLK, NTH, 0, stream>>>(node_type, pos, adj, vcount, rin, cin, gmin,
      W1, b1, W2, b2, bmu, blv,
      (const uint4*)B1, (const uint4*)B2, WnX, bn, WmuT, WlvT, order, (float*)d_out);
}